// Round 13
// baseline (300.794 us; speedup 1.0000x reference)
//
#include <hip/hip_runtime.h>
#include <hip/hip_bf16.h>

#define HID 1024
#define HEADS 16
#define HEAD 64
#define RELN 63
#define SEQ 512
#define BATCH 16
#define NROWS (SEQ*BATCH)      // 8192
#define MEXT 8320              // 8192 + 63, padded to 65*128
#define NQKV 3072
#define LNEPS 1e-7f
// 1/sqrt(3*64) * log2(e): folded into Q at the QKV-GEMM epilogue (base-2 domain)
#define SCALE2 (0.07216878364870323f * 1.4426950408889634f)

typedef __attribute__((ext_vector_type(4))) float  f32x4;
typedef __attribute__((ext_vector_type(8))) short  s16x8;
typedef __attribute__((ext_vector_type(4))) ushort u16x4;

static __device__ __forceinline__ ushort f2bf(float f) {
  __hip_bfloat16 h = __float2bfloat16(f);        // native RNE cvt
  return *reinterpret_cast<ushort*>(&h);
}
static __device__ __forceinline__ float bf2f(ushort u) {
  union { unsigned u; float f; } v; v.u = ((unsigned)u) << 16;
  return v.f;
}

// ---------------- prep: mask dtype detect + mask01 + bucket idx table + bias concat ------
__global__ void k_prep(const void* mask_raw, const float* bqk, const float* bv,
                       ushort* mask01, int* idx_tab, float* bcat) {
  __shared__ int s_isbool;
  int tid = threadIdx.x;
  if (tid == 0) s_isbool = 0;
  __syncthreads();
  const unsigned* mu = (const unsigned*)mask_raw;
  int bad = 0;
  for (int i = tid; i < 2048; i += 256) if (mu[i] > 1u) bad = 1;
  if (bad) s_isbool = 1;              // benign race: any writer writes 1
  __syncthreads();
  int isbool = s_isbool;
  const unsigned char* m8 = (const unsigned char*)mask_raw;
  const int* m32 = (const int*)mask_raw;
  for (int i = tid; i < BATCH*SEQ; i += 256) {
    int m = isbool ? (int)m8[i] : m32[i];
    mask01[i] = m ? 1 : 0;
  }
  for (int i = tid; i < 1023; i += 256) {
    int r = i - 511;
    int a = r < 0 ? -r : r;
    int absp = (a < 16) ? 15 : (a < 511 ? a : 511);
    int idx;
    if (absp <= 16) idx = 31 + r;
    else {
      float v = logf((float)absp / 16.0f) / logf(511.0f / 16.0f) * 15.0f;
      int lp = (int)ceilf(v) + 16;
      idx = 31 + (r > 0 ? lp : -lp);
    }
    idx_tab[i] = idx;
  }
  for (int i = tid; i < 2048; i += 256) bcat[i] = bqk[i];
  for (int i = tid; i < 1024; i += 256) bcat[2048 + i] = bv[i];
}

// ---------------- f32 -> bf16 weight conversion, vectorized x4 ---------------------------
__global__ __launch_bounds__(256) void k_convert(const float* wqk, const float* wv, const float* wo,
                                                 ushort* wcat, ushort* wo_b) {
  int c = blockIdx.x * 256 + threadIdx.x;    // 1,048,576 chunks of 4 elems
  f32x4 x; ushort* dst;
  if (c < 524288)      { x = *(const f32x4*)(wqk + (size_t)c * 4);            dst = wcat + (size_t)c * 4; }
  else if (c < 786432) { x = *(const f32x4*)(wv  + (size_t)(c - 524288) * 4); dst = wcat + (size_t)c * 4; }
  else                 { x = *(const f32x4*)(wo  + (size_t)(c - 786432) * 4); dst = wo_b + (size_t)(c - 786432) * 4; }
  u16x4 o = { f2bf(x[0]), f2bf(x[1]), f2bf(x[2]), f2bf(x[3]) };
  *(u16x4*)dst = o;
}

// ---------------- LN1 (no affine) -> bf16, plus rel-embedding rows + zero pad ------------
__global__ __launch_bounds__(256) void k_ln1(const float* hid, const float* rel, ushort* h_ext) {
  int row = blockIdx.x, tid = threadIdx.x;
  __shared__ float red[8];
  if (row < NROWS) {
    const float* src = hid + (size_t)row * HID;
    f32x4 x = *(const f32x4*)(src + tid * 4);
    float s = x[0] + x[1] + x[2] + x[3];
    #pragma unroll
    for (int m = 1; m < 64; m <<= 1) s += __shfl_xor(s, m);
    if ((tid & 63) == 0) red[tid >> 6] = s;
    __syncthreads();
    float mean = (red[0] + red[1] + red[2] + red[3]) * (1.0f / HID);
    float d0 = x[0] - mean, d1 = x[1] - mean, d2 = x[2] - mean, d3 = x[3] - mean;
    float sq = d0*d0 + d1*d1 + d2*d2 + d3*d3;
    #pragma unroll
    for (int m = 1; m < 64; m <<= 1) sq += __shfl_xor(sq, m);
    __syncthreads();
    if ((tid & 63) == 0) red[4 + (tid >> 6)] = sq;
    __syncthreads();
    float var = (red[4] + red[5] + red[6] + red[7]) * (1.0f / HID);
    float rs = rsqrtf(var + LNEPS);
    u16x4 o = { f2bf(d0*rs), f2bf(d1*rs), f2bf(d2*rs), f2bf(d3*rs) };
    *(u16x4*)(h_ext + (size_t)row * HID + tid * 4) = o;
  } else if (row < NROWS + RELN) {
    const float* src = rel + (size_t)(row - NROWS) * HID;
    f32x4 x = *(const f32x4*)(src + tid * 4);
    u16x4 o = { f2bf(x[0]), f2bf(x[1]), f2bf(x[2]), f2bf(x[3]) };
    *(u16x4*)(h_ext + (size_t)row * HID + tid * 4) = o;
  } else {
    u16x4 z = { 0, 0, 0, 0 };
    *(u16x4*)(h_ext + (size_t)row * HID + tid * 4) = z;
  }
}

// ---------------- QKV GEMM: 256x128 tile, 8 waves, BK=64, swizzled global_load_lds -------
// Q columns (col<1024) pre-scaled by SCALE2 at the epilogue (base-2 attention domain).
__global__ __launch_bounds__(512) void k_gemm256(const ushort* A, const ushort* Bw, const float* bias,
                                                 ushort* Cb, int M, int N, int K) {
  __shared__ char smem[49152];
  char* As = smem;              // 256 x 64 bf16 = 32 KB
  char* Bs = smem + 32768;      // 128 x 64 bf16 = 16 KB
  int tid = threadIdx.x, lane = tid & 63, w = tid >> 6;
  int nbn = N >> 7;
  int per = gridDim.x >> 3;
  int gl = (blockIdx.x & 7) * per + (blockIdx.x >> 3);
  int bm = gl / nbn, bn = gl % nbn;
  int wr = w >> 1, wc = w & 1;           // 4x2 wave grid, 64x64 per wave
  int g = lane >> 4, r = lane & 15;
  f32x4 acc[4][4] = {};
  for (int ko = 0; ko < K; ko += 64) {
    __syncthreads();
    #pragma unroll
    for (int c = 0; c < 4; ++c) {        // A: 2048 chunks of 16B
      int chunk = c * 512 + tid;
      int row = chunk >> 3;
      int kbs = ((chunk & 7) << 4) ^ ((row & 7) << 4);
      int ar = bm * 256 + row; ar = ar < M ? ar : M - 1;
      const char* gA = (const char*)(A + (size_t)ar * K + ko) + kbs;
      __builtin_amdgcn_global_load_lds((const __attribute__((address_space(1))) void*)gA,
                                       (__attribute__((address_space(3))) void*)(As + c * 8192 + w * 1024),
                                       16, 0, 0);
    }
    #pragma unroll
    for (int c = 0; c < 2; ++c) {        // B: 1024 chunks of 16B
      int chunk = c * 512 + tid;
      int row = chunk >> 3;
      int kbs = ((chunk & 7) << 4) ^ ((row & 7) << 4);
      const char* gB = (const char*)(Bw + (size_t)(bn * 128 + row) * K + ko) + kbs;
      __builtin_amdgcn_global_load_lds((const __attribute__((address_space(1))) void*)gB,
                                       (__attribute__((address_space(3))) void*)(Bs + c * 8192 + w * 1024),
                                       16, 0, 0);
    }
    __syncthreads();
    #pragma unroll
    for (int kk = 0; kk < 2; ++kk) {
      s16x8 af[4], bf[4];
      #pragma unroll
      for (int mt = 0; mt < 4; ++mt) {
        int row = wr * 64 + mt * 16 + r;
        int kb = (kk * 64 + g * 16) ^ ((row & 7) << 4);
        af[mt] = *(const s16x8*)(As + row * 128 + kb);
      }
      #pragma unroll
      for (int nt = 0; nt < 4; ++nt) {
        int row = wc * 64 + nt * 16 + r;
        int kb = (kk * 64 + g * 16) ^ ((row & 7) << 4);
        bf[nt] = *(const s16x8*)(Bs + row * 128 + kb);
      }
      #pragma unroll
      for (int mt = 0; mt < 4; ++mt)
        #pragma unroll
        for (int nt = 0; nt < 4; ++nt)
          acc[mt][nt] = __builtin_amdgcn_mfma_f32_16x16x32_bf16(af[mt], bf[nt], acc[mt][nt], 0, 0, 0);
    }
  }
  #pragma unroll
  for (int nt = 0; nt < 4; ++nt) {
    int col = bn * 128 + wc * 64 + nt * 16 + r;
    float bvv = bias[col];
    float sc = (col < 1024) ? SCALE2 : 1.0f;   // fold attention scale into Q (and qpos)
    #pragma unroll
    for (int mt = 0; mt < 4; ++mt) {
      int row0 = bm * 256 + wr * 64 + mt * 16 + g * 4;
      #pragma unroll
      for (int i = 0; i < 4; ++i) {
        int row = row0 + i;
        if (row < M) Cb[(size_t)row * N + col] = f2bf((acc[mt][nt][i] + bvv) * sc);
      }
    }
  }
}

// ---------------- output GEMM: 128x128 tile, split-K=2, bf16 partials --------------------
__global__ __launch_bounds__(256) void k_gemm_sk(const ushort* A, const ushort* Bw, const float* bias,
                                                 ushort* C0, ushort* C1) {
  const int N = 1024, K = 1024;
  __shared__ char smem[32768];
  char* As = smem;
  char* Bs = smem + 16384;
  int tid = threadIdx.x, lane = tid & 63, w = tid >> 6;
  int per = gridDim.x >> 3;
  int gl = (blockIdx.x & 7) * per + (blockIdx.x >> 3);
  int bn = gl & 7, ks = (gl >> 3) & 1, bm = gl >> 4;
  int wr = w >> 1, wc = w & 1;
  int g = lane >> 4, r = lane & 15;
  f32x4 acc[4][4] = {};
  for (int ko = ks * 512; ko < ks * 512 + 512; ko += 64) {
    __syncthreads();
    #pragma unroll
    for (int c = 0; c < 4; ++c) {
      int chunk = c * 256 + tid;
      int row = chunk >> 3;
      int kbs = ((chunk & 7) << 4) ^ ((row & 7) << 4);
      const char* gA = (const char*)(A + (size_t)(bm * 128 + row) * K + ko) + kbs;
      const char* gB = (const char*)(Bw + (size_t)(bn * 128 + row) * K + ko) + kbs;
      __builtin_amdgcn_global_load_lds((const __attribute__((address_space(1))) void*)gA,
                                       (__attribute__((address_space(3))) void*)(As + c * 4096 + w * 1024),
                                       16, 0, 0);
      __builtin_amdgcn_global_load_lds((const __attribute__((address_space(1))) void*)gB,
                                       (__attribute__((address_space(3))) void*)(Bs + c * 4096 + w * 1024),
                                       16, 0, 0);
    }
    __syncthreads();
    #pragma unroll
    for (int kk = 0; kk < 2; ++kk) {
      s16x8 af[4], bf[4];
      #pragma unroll
      for (int mt = 0; mt < 4; ++mt) {
        int row = wr * 64 + mt * 16 + r;
        int kb = (kk * 64 + g * 16) ^ ((row & 7) << 4);
        af[mt] = *(const s16x8*)(As + row * 128 + kb);
      }
      #pragma unroll
      for (int nt = 0; nt < 4; ++nt) {
        int row = wc * 64 + nt * 16 + r;
        int kb = (kk * 64 + g * 16) ^ ((row & 7) << 4);
        bf[nt] = *(const s16x8*)(Bs + row * 128 + kb);
      }
      #pragma unroll
      for (int mt = 0; mt < 4; ++mt)
        #pragma unroll
        for (int nt = 0; nt < 4; ++nt)
          acc[mt][nt] = __builtin_amdgcn_mfma_f32_16x16x32_bf16(af[mt], bf[nt], acc[mt][nt], 0, 0, 0);
    }
  }
  ushort* C = ks ? C1 : C0;
  #pragma unroll
  for (int nt = 0; nt < 4; ++nt) {
    int col = bn * 128 + wc * 64 + nt * 16 + r;
    float bvv = ks ? 0.0f : bias[col];
    #pragma unroll
    for (int mt = 0; mt < 4; ++mt) {
      int row0 = bm * 128 + wr * 64 + mt * 16 + g * 4;
      #pragma unroll
      for (int i = 0; i < 4; ++i)
        C[(size_t)(row0 + i) * N + col] = f2bf(acc[mt][nt][i] + bvv);
    }
  }
}

// ---------------- positional score tables (bf16, scale inherited from Q, mask in pk) -----
__global__ __launch_bounds__(256) void k_pos(const ushort* qkv, const ushort* mask01,
                                             ushort* qp, ushort* pk) {
  int bh = blockIdx.x;
  int b = bh >> 4, h = bh & 15;
  int tid = threadIdx.x, lane = tid & 63, w = tid >> 6;
  int g = lane >> 4, r = lane & 15;
  __shared__ ushort mb[512];
  for (int i = tid; i < 512; i += 256) mb[i] = mask01[b * SEQ + i];
  __syncthreads();
  s16x8 bkp[4][2], bqp[4][2];   // kpos / qpos B-fragments (t = nt*16+r)
  #pragma unroll
  for (int nt = 0; nt < 4; ++nt)
    #pragma unroll
    for (int kk = 0; kk < 2; ++kk) {
      size_t rowp = (size_t)(NROWS + nt * 16 + r);
      int colq = h * 64 + kk * 32 + g * 8;
      bqp[nt][kk] = *(const s16x8*)(qkv + rowp * NQKV + colq);          // qpos (pre-scaled)
      bkp[nt][kk] = *(const s16x8*)(qkv + rowp * NQKV + 1024 + colq);   // kpos (unscaled)
    }
  for (int cc = 0; cc < 8; ++cc) {
    int rowbase = cc * 64 + w * 16;
    s16x8 aq[2], ak[2];
    #pragma unroll
    for (int kk = 0; kk < 2; ++kk) {
      size_t rowq = (size_t)((rowbase + r) * 16 + b);
      int colq = h * 64 + kk * 32 + g * 8;
      aq[kk] = *(const s16x8*)(qkv + rowq * NQKV + colq);               // q (pre-scaled)
      ak[kk] = *(const s16x8*)(qkv + rowq * NQKV + 1024 + colq);        // k (unscaled)
    }
    f32x4 accq[4] = {}, acck[4] = {};
    #pragma unroll
    for (int kk = 0; kk < 2; ++kk)
      #pragma unroll
      for (int nt = 0; nt < 4; ++nt) {
        accq[nt] = __builtin_amdgcn_mfma_f32_16x16x32_bf16(aq[kk], bkp[nt][kk], accq[nt], 0, 0, 0);
        acck[nt] = __builtin_amdgcn_mfma_f32_16x16x32_bf16(ak[kk], bqp[nt][kk], acck[nt], 0, 0, 0);
      }
    #pragma unroll
    for (int nt = 0; nt < 4; ++nt)
      #pragma unroll
      for (int i = 0; i < 4; ++i) {
        int q = rowbase + g * 4 + i;
        int t = nt * 16 + r;
        float biasv = mb[q] ? -1e9f : 0.0f;          // key-mask baked into pk rows
        qp[(size_t)bh * SEQ * 64 + q * 64 + t] = f2bf(accq[nt][i]);
        pk[(size_t)bh * SEQ * 64 + q * 64 + t] = f2bf(acck[nt][i] + biasv);
      }
  }
}

// ---------------- V transpose + K repack (pure copies): vt[b,h,d,l], kc[b,h,l,d] ---------
__global__ __launch_bounds__(256) void k_vt(const ushort* qkv, ushort* vt, ushort* kc) {
  int bid = blockIdx.x;
  int bh = bid >> 3, lt = bid & 7;
  int b = bh >> 4, h = bh & 15;
  __shared__ ushort tile[64][72];
  int tid = threadIdx.x;
  #pragma unroll
  for (int c = 0; c < 2; ++c) {
    int e = (c * 256 + tid) * 8;
    int l = e >> 6, d0 = e & 63;
    size_t row = (size_t)((lt * 64 + l) * 16 + b);
    s16x8 kv = *(const s16x8*)(qkv + row * NQKV + 1024 + h * 64 + d0);
    *(s16x8*)(kc + ((size_t)bh * SEQ + lt * 64 + l) * 64 + d0) = kv;   // contiguous K rows
    *(s16x8*)&tile[l][d0] = *(const s16x8*)(qkv + row * NQKV + 2048 + h * 64 + d0);
  }
  __syncthreads();
  #pragma unroll
  for (int c = 0; c < 2; ++c) {
    int e = (c * 256 + tid) * 8;
    int d = e >> 6, l0 = e & 63;
    ushort tmp[8];
    #pragma unroll
    for (int j = 0; j < 8; ++j) tmp[j] = tile[l0 + j][d];
    *(s16x8*)(vt + (size_t)(bh * 64 + d) * SEQ + lt * 64 + l0) = *(s16x8*)tmp;
  }
}

// ---------------- fused attention: q-quarter blocks, pk half-staged, 2 blocks/CU ---------
// Block = (bh, q-quarter 128 rows): each of 8 waves owns ONE 16-row q-subtile.
// pk staged in halves (restaged once at kt==4). LDS 71,680 B -> 2 blocks/CU via LDS alone;
// NO register cap (R12's __launch_bounds__(512,4) forced VGPR=64 -> 14MB scratch spill).
__global__ __launch_bounds__(512) void k_attn(const ushort* qkv, const ushort* qp_all, const ushort* pk_all,
                                              const ushort* kc, const ushort* vt,
                                              const int* idx_tab, ushort* ctx) {
  int bid = blockIdx.x;
  int slot = bid >> 3;                     // [0,128)
  int bh = (bid & 7) * 32 + (slot >> 2);   // all 4 q-quarter blocks of a bh on one XCD
  int qq = slot & 3;                       // q-quarter (128 rows)
  int b = bh >> 4, h = bh & 15;
  int tid = threadIdx.x, lane = tid & 63, w = tid >> 6;
  int g = lane >> 4, r = lane & 15;

  __shared__ ushort pk_s[256][68];   // 34,816 B  half-k pk table (restaged once)
  __shared__ ushort qp_s[128][68];   // 17,408 B  this quarter's qp rows
  __shared__ ushort p_s[8][16][68];  // 17,408 B  per-wave P staging (stride 68: conflict-free)
  __shared__ ushort idx_s[1024];     //  2,048 B  -> total 71,680 B

  const ushort* qpsrc = qp_all + (size_t)bh * SEQ * 64 + (size_t)qq * 128 * 64;
  const ushort* pksrc = pk_all + (size_t)bh * SEQ * 64;
  const char*   kcb   = (const char*)(kc + (size_t)bh * SEQ * 64);   // [l][d] 128B rows

  // ---- prologue: stage qp(128 rows), pk(first 256 rows), idx; load aq; ONE barrier ----
  #pragma unroll
  for (int c = 0; c < 2; ++c) {            // qp: 1024 chunks of 8 u16
    int chunk = c * 512 + tid;
    int row = chunk >> 3, col8 = (chunk & 7) * 8;
    s16x8 v = *(const s16x8*)(qpsrc + (size_t)row * 64 + col8);
    u16x4 lo = { (ushort)v[0], (ushort)v[1], (ushort)v[2], (ushort)v[3] };
    u16x4 hi = { (ushort)v[4], (ushort)v[5], (ushort)v[6], (ushort)v[7] };
    *(u16x4*)&qp_s[row][col8] = lo;
    *(u16x4*)&qp_s[row][col8 + 4] = hi;
  }
  #pragma unroll
  for (int c = 0; c < 4; ++c) {            // pk half: 2048 chunks of 8 u16
    int chunk = c * 512 + tid;
    int row = chunk >> 3, col8 = (chunk & 7) * 8;
    s16x8 v = *(const s16x8*)(pksrc + (size_t)row * 64 + col8);
    u16x4 lo = { (ushort)v[0], (ushort)v[1], (ushort)v[2], (ushort)v[3] };
    u16x4 hi = { (ushort)v[4], (ushort)v[5], (ushort)v[6], (ushort)v[7] };
    *(u16x4*)&pk_s[row][col8] = lo;
    *(u16x4*)&pk_s[row][col8 + 4] = hi;
  }
  for (int i = tid; i < 1023; i += 512) idx_s[i] = (ushort)idx_tab[i];
  s16x8 aq[2];                             // Q fragments (pre-scaled by SCALE2)
  int qrow = qq * 128 + w * 16 + r;        // this thread's q (A-col r within wave tile)
  #pragma unroll
  for (int kk = 0; kk < 2; ++kk)
    aq[kk] = *(const s16x8*)(qkv + ((size_t)qrow * 16 + b) * NQKV + h * 64 + kk * 32 + g * 8);
  __syncthreads();

  float m_i = -3e38f, l_i = 0.0f;
  f32x4 o_acc[4] = {};
  const ushort* qprow = &qp_s[w * 16 + r][0];
  const int qg511 = qrow + 511;

  for (int kt = 0; kt < 8; ++kt) {
    // ---- restage pk for k in [256,512) once, between kt=3 and kt=4 ----
    if (kt == 4) {
      __syncthreads();                     // all waves done reading pk_s (k<256)
      #pragma unroll
      for (int c = 0; c < 4; ++c) {
        int chunk = c * 512 + tid;
        int row = chunk >> 3, col8 = (chunk & 7) * 8;
        s16x8 v = *(const s16x8*)(pksrc + (size_t)(256 + row) * 64 + col8);
        u16x4 lo = { (ushort)v[0], (ushort)v[1], (ushort)v[2], (ushort)v[3] };
        u16x4 hi = { (ushort)v[4], (ushort)v[5], (ushort)v[6], (ushort)v[7] };
        *(u16x4*)&pk_s[row][col8] = lo;
        *(u16x4*)&pk_s[row][col8 + 4] = hi;
      }
      __syncthreads();                     // pk_s (k>=256) visible
    }

    // K and V fragments straight from global (L2-shared across the block's 8 waves)
    s16x8 kf[4][2], vf[2][4];
    #pragma unroll
    for (int nt = 0; nt < 4; ++nt)
      #pragma unroll
      for (int kk = 0; kk < 2; ++kk)
        kf[nt][kk] = *(const s16x8*)(kcb + (size_t)(kt * 64 + nt * 16 + r) * 128 + kk * 64 + g * 16);
    #pragma unroll
    for (int kk = 0; kk < 2; ++kk)
      #pragma unroll
      for (int nt = 0; nt < 4; ++nt)
        vf[kk][nt] = *(const s16x8*)(vt + (size_t)(bh * 64 + nt * 16 + r) * SEQ + kt * 64 + kk * 32 + g * 8);

    // ---- swapped QK^T: lane holds S^T for q = r(+wave q-base), k = nt*16+g*4+i ----
    f32x4 s[4];
    __builtin_amdgcn_s_setprio(1);
    #pragma unroll
    for (int nt = 0; nt < 4; ++nt) {
      f32x4 a = {};
      #pragma unroll
      for (int kk = 0; kk < 2; ++kk)
        a = __builtin_amdgcn_mfma_f32_16x16x32_bf16(kf[nt][kk], aq[kk], a, 0, 0, 0);   // A=K, B=Q
      s[nt] = a;
    }
    __builtin_amdgcn_s_setprio(0);

    // ---- gather: v = c2c + qp_s[q][t] + pk_s[(k&255)][t]  (scale folded, mask in pk) ----
    float m_loc = -3e38f;
    #pragma unroll
    for (int nt = 0; nt < 4; ++nt) {
      #pragma unroll
      for (int i = 0; i < 4; ++i) {
        int kg = kt * 64 + nt * 16 + g * 4 + i;
        int t = idx_s[qg511 - kg];
        float v = s[nt][i] + bf2f(qprow[t]) + bf2f(pk_s[kg & 255][t]);
        s[nt][i] = v;
        m_loc = fmaxf(m_loc, v);
      }
    }

    // ---- row max across the 4 g-lanes holding q = r ----
    float mx = fmaxf(m_loc, __shfl_xor(m_loc, 16));
    mx = fmaxf(mx, __shfl_xor(mx, 32));

    // ---- T13 defer-rescale (base-2 threshold 8) ----
    if (__any(mx > m_i + 8.0f)) {
      float mnew = fmaxf(m_i, mx);
      float rs = exp2f(m_i - mnew);
      m_i = mnew;
      l_i *= rs;
      float rsb[4];
      #pragma unroll
      for (int i = 0; i < 4; ++i) rsb[i] = __shfl(rs, g * 4 + i);   // rs for q = g*4+i
      #pragma unroll
      for (int nt = 0; nt < 4; ++nt)
        #pragma unroll
        for (int i = 0; i < 4; ++i) o_acc[nt][i] *= rsb[i];
    }

    // ---- exp2 + P pack (b64 LDS writes), psum ----
    float psum = 0.0f;
    #pragma unroll
    for (int nt = 0; nt < 4; ++nt) {
      u16x4 pk4;
      #pragma unroll
      for (int i = 0; i < 4; ++i) {
        float pe = exp2f(s[nt][i] - m_i);   // masked: huge negative -> exact 0
        psum += pe;
        pk4[i] = f2bf(pe);
      }
      *(u16x4*)&p_s[w][r][nt * 16 + g * 4] = pk4;
    }
    psum += __shfl_xor(psum, 16);
    psum += __shfl_xor(psum, 32);
    l_i += psum;

    // ---- PV (2 x b64 p reads; per-wave roundtrip ordered by lgkmcnt) ----
    __builtin_amdgcn_s_setprio(1);
    #pragma unroll
    for (int kk = 0; kk < 2; ++kk) {
      u16x4 lo = *(const u16x4*)&p_s[w][r][kk * 32 + g * 8];
      u16x4 hi = *(const u16x4*)&p_s[w][r][kk * 32 + g * 8 + 4];
      s16x8 pa = { (short)lo[0], (short)lo[1], (short)lo[2], (short)lo[3],
                   (short)hi[0], (short)hi[1], (short)hi[2], (short)hi[3] };
      #pragma unroll
      for (int nt = 0; nt < 4; ++nt)
        o_acc[nt] = __builtin_amdgcn_mfma_f32_16x16x32_bf16(pa, vf[kk][nt], o_acc[nt], 0, 0, 0);
    }
    __builtin_amdgcn_s_setprio(0);
  }

  float lb[4];
  #pragma unroll
  for (int i = 0; i < 4; ++i) lb[i] = __shfl(l_i, g * 4 + i);   // l for q = g*4+i
  #pragma unroll
  for (int i = 0; i < 4; ++i) {
    float inv = lb[i] > 0.0f ? 1.0f / lb[i] : 0.0f;
    int lq = qq * 128 + w * 16 + g * 4 + i;
    size_t rowc = (size_t)(lq * 16 + b);
    #pragma unroll
    for (int nt = 0; nt < 4; ++nt)
      ctx[rowc * HID + h * 64 + nt * 16 + r] = f2bf(o_acc[nt][i] * inv);
  }
}

// ---------------- LN2 (affine), two bf16 partials in -> f32 out --------------------------
__global__ __launch_bounds__(256) void k_ln2(const ushort* t0, const ushort* t1,
                                             const float* gamma, const float* beta, float* out) {
  int row = blockIdx.x, tid = threadIdx.x;
  __shared__ float red[8];
  u16x4 xa = *(const u16x4*)(t0 + (size_t)row * HID + tid * 4);
  u16x4 xb = *(const u16x4*)(t1 + (size_t)row * HID + tid * 4);
  float x[4];
  #pragma unroll
  for (int j = 0; j < 4; ++j) x[j] = bf2f(xa[j]) + bf2f(xb[j]);
  float s = x[0] + x[1] + x[2] + x[3];
  #pragma unroll
  for (int m = 1; m < 64; m <<= 1) s += __shfl_xor(s, m);
  if ((tid & 63) == 0) red[tid >> 6] = s;
  __syncthreads();
  float mean = (red[0] + red[1] + red[2] + red[3]) * (1.0f / HID);
  float d[4]; float sq = 0.0f;
  #pragma unroll
  for (int j = 0; j < 4; ++j) { d[j] = x[j] - mean; sq += d[j] * d[j]; }
  #pragma unroll
  for (int m = 1; m < 64; m <<= 1) sq += __shfl_xor(sq, m);
  __syncthreads();
  if ((tid & 63) == 0) red[4 + (tid >> 6)] = sq;
  __syncthreads();
  float var = (red[4] + red[5] + red[6] + red[7]) * (1.0f / HID);
  float rs = rsqrtf(var + LNEPS);
  f32x4 o;
  #pragma unroll
  for (int j = 0; j < 4; ++j) o[j] = d[j] * rs * gamma[tid * 4 + j] + beta[tid * 4 + j];
  *(f32x4*)(out + (size_t)row * HID + tid * 4) = o;
}

// ---------------- launch -----------------------------------------------------------------
extern "C" void kernel_launch(void* const* d_in, const int* in_sizes, int n_in,
                              void* d_out, int out_size, void* d_ws, size_t ws_size,
                              hipStream_t stream) {
  (void)in_sizes; (void)n_in; (void)out_size; (void)ws_size;
  const float* hid  = (const float*)d_in[0];
  const void*  mask = d_in[1];
  const float* rel  = (const float*)d_in[2];
  const float* wqk  = (const float*)d_in[3];
  const float* bqk  = (const float*)d_in[4];
  const float* wv   = (const float*)d_in[5];
  const float* bv   = (const float*)d_in[6];
  const float* wo   = (const float*)d_in[7];
  const float* bo   = (const float*)d_in[8];
  const float* ln_g = (const float*)d_in[9];
  const float* ln_b = (const float*)d_in[10];

  char* ws = (char*)d_ws;
  ushort* wcat     = (ushort*)(ws);                 //  6,291,456
  ushort* wo_b     = (ushort*)(ws + 6291456);       //  2,097,152
  float*  bcat     = (float*) (ws + 8388608);       //     12,288
  ushort* mask01   = (ushort*)(ws + 8400896);       //     16,384 (region 32,768)
  int*    idx_tab  = (int*)   (ws + 8433664);       //      4,096
  ushort* h_ext    = (ushort*)(ws + 8437760);       // 17,039,360  (reused as ctx)
  ushort* qkv      = (ushort*)(ws + 25477120);      // 51,118,080
  ushort* qp_b     = (ushort*)(ws + 76595200);      // 16,777,216 (bf16, scale inherited)
  ushort* pk_b     = (ushort*)(ws + 93372416);      // 16,777,216 (bf16, scale + mask)
  ushort* vt       = (ushort*)(ws + 110149632);     // 16,777,216
  char*   tmpr     = (ws + 126926848);              // 33,554,432 region
  ushort* ctx = h_ext;
  ushort* kc   = (ushort*)tmpr;                     // dead once k_attn finishes
  ushort* tmp0 = (ushort*)tmpr;                     // split-K partial 0 (16,777,216)
  ushort* tmp1 = (ushort*)(tmpr + 16777216);        // split-K partial 1 (16,777,216)

  k_prep<<<1, 256, 0, stream>>>(mask, bqk, bv, mask01, idx_tab, bcat);
  k_convert<<<4096, 256, 0, stream>>>(wqk, wv, wo, wcat, wo_b);
  k_ln1<<<MEXT, 256, 0, stream>>>(hid, rel, h_ext);
  k_gemm256<<<33 * (NQKV / 128), 512, 0, stream>>>(h_ext, wcat, bcat, qkv, MEXT, NQKV, 1024);
  k_pos<<<256, 256, 0, stream>>>(qkv, mask01, qp_b, pk_b);
  k_vt<<<2048, 256, 0, stream>>>(qkv, vt, kc);
  k_attn<<<1024, 512, 0, stream>>>(qkv, qp_b, pk_b, kc, vt, idx_tab, ctx);
  k_gemm_sk<<<1024, 256, 0, stream>>>(ctx, wo_b, bo, tmp0, tmp1);
  k_ln2<<<NROWS, 256, 0, stream>>>(tmp0, tmp1, ln_g, ln_b, (float*)d_out);
}

// Round 14
// 249.675 us; speedup vs baseline: 1.2047x; 1.2047x over previous
//
#include <hip/hip_runtime.h>
#include <hip/hip_bf16.h>

#define HID 1024
#define HEADS 16
#define HEAD 64
#define RELN 63
#define SEQ 512
#define BATCH 16
#define NROWS (SEQ*BATCH)      // 8192
#define MEXT 8320              // 8192 + 63, padded to 65*128
#define NQKV 3072
#define LNEPS 1e-7f
// 1/sqrt(3*64) * log2(e): folded into Q at the QKV-GEMM epilogue (base-2 domain)
#define SCALE2 (0.07216878364870323f * 1.4426950408889634f)

typedef __attribute__((ext_vector_type(4))) float  f32x4;
typedef __attribute__((ext_vector_type(8))) short  s16x8;
typedef __attribute__((ext_vector_type(4))) ushort u16x4;

static __device__ __forceinline__ ushort f2bf(float f) {
  __hip_bfloat16 h = __float2bfloat16(f);        // native RNE cvt
  return *reinterpret_cast<ushort*>(&h);
}
static __device__ __forceinline__ float bf2f(ushort u) {
  union { unsigned u; float f; } v; v.u = ((unsigned)u) << 16;
  return v.f;
}

// ---------------- prep: mask dtype detect + mask01 + bucket idx table + bias concat ------
__global__ void k_prep(const void* mask_raw, const float* bqk, const float* bv,
                       ushort* mask01, int* idx_tab, float* bcat) {
  __shared__ int s_isbool;
  int tid = threadIdx.x;
  if (tid == 0) s_isbool = 0;
  __syncthreads();
  const unsigned* mu = (const unsigned*)mask_raw;
  int bad = 0;
  for (int i = tid; i < 2048; i += 256) if (mu[i] > 1u) bad = 1;
  if (bad) s_isbool = 1;              // benign race: any writer writes 1
  __syncthreads();
  int isbool = s_isbool;
  const unsigned char* m8 = (const unsigned char*)mask_raw;
  const int* m32 = (const int*)mask_raw;
  for (int i = tid; i < BATCH*SEQ; i += 256) {
    int m = isbool ? (int)m8[i] : m32[i];
    mask01[i] = m ? 1 : 0;
  }
  for (int i = tid; i < 1023; i += 256) {
    int r = i - 511;
    int a = r < 0 ? -r : r;
    int absp = (a < 16) ? 15 : (a < 511 ? a : 511);
    int idx;
    if (absp <= 16) idx = 31 + r;
    else {
      float v = logf((float)absp / 16.0f) / logf(511.0f / 16.0f) * 15.0f;
      int lp = (int)ceilf(v) + 16;
      idx = 31 + (r > 0 ? lp : -lp);
    }
    idx_tab[i] = idx;
  }
  for (int i = tid; i < 2048; i += 256) bcat[i] = bqk[i];
  for (int i = tid; i < 1024; i += 256) bcat[2048 + i] = bv[i];
}

// ---------------- f32 -> bf16 weight conversion, vectorized x4 ---------------------------
__global__ __launch_bounds__(256) void k_convert(const float* wqk, const float* wv, const float* wo,
                                                 ushort* wcat, ushort* wo_b) {
  int c = blockIdx.x * 256 + threadIdx.x;    // 1,048,576 chunks of 4 elems
  f32x4 x; ushort* dst;
  if (c < 524288)      { x = *(const f32x4*)(wqk + (size_t)c * 4);            dst = wcat + (size_t)c * 4; }
  else if (c < 786432) { x = *(const f32x4*)(wv  + (size_t)(c - 524288) * 4); dst = wcat + (size_t)c * 4; }
  else                 { x = *(const f32x4*)(wo  + (size_t)(c - 786432) * 4); dst = wo_b + (size_t)(c - 786432) * 4; }
  u16x4 o = { f2bf(x[0]), f2bf(x[1]), f2bf(x[2]), f2bf(x[3]) };
  *(u16x4*)dst = o;
}

// ---------------- LN1 (no affine) -> bf16, plus rel-embedding rows + zero pad ------------
__global__ __launch_bounds__(256) void k_ln1(const float* hid, const float* rel, ushort* h_ext) {
  int row = blockIdx.x, tid = threadIdx.x;
  __shared__ float red[8];
  if (row < NROWS) {
    const float* src = hid + (size_t)row * HID;
    f32x4 x = *(const f32x4*)(src + tid * 4);
    float s = x[0] + x[1] + x[2] + x[3];
    #pragma unroll
    for (int m = 1; m < 64; m <<= 1) s += __shfl_xor(s, m);
    if ((tid & 63) == 0) red[tid >> 6] = s;
    __syncthreads();
    float mean = (red[0] + red[1] + red[2] + red[3]) * (1.0f / HID);
    float d0 = x[0] - mean, d1 = x[1] - mean, d2 = x[2] - mean, d3 = x[3] - mean;
    float sq = d0*d0 + d1*d1 + d2*d2 + d3*d3;
    #pragma unroll
    for (int m = 1; m < 64; m <<= 1) sq += __shfl_xor(sq, m);
    __syncthreads();
    if ((tid & 63) == 0) red[4 + (tid >> 6)] = sq;
    __syncthreads();
    float var = (red[4] + red[5] + red[6] + red[7]) * (1.0f / HID);
    float rs = rsqrtf(var + LNEPS);
    u16x4 o = { f2bf(d0*rs), f2bf(d1*rs), f2bf(d2*rs), f2bf(d3*rs) };
    *(u16x4*)(h_ext + (size_t)row * HID + tid * 4) = o;
  } else if (row < NROWS + RELN) {
    const float* src = rel + (size_t)(row - NROWS) * HID;
    f32x4 x = *(const f32x4*)(src + tid * 4);
    u16x4 o = { f2bf(x[0]), f2bf(x[1]), f2bf(x[2]), f2bf(x[3]) };
    *(u16x4*)(h_ext + (size_t)row * HID + tid * 4) = o;
  } else {
    u16x4 z = { 0, 0, 0, 0 };
    *(u16x4*)(h_ext + (size_t)row * HID + tid * 4) = z;
  }
}

// ---------------- QKV GEMM: 256x128 tile, 8 waves, BK=64, swizzled global_load_lds -------
// Q columns (col<1024) pre-scaled by SCALE2 at the epilogue (base-2 attention domain).
__global__ __launch_bounds__(512) void k_gemm256(const ushort* A, const ushort* Bw, const float* bias,
                                                 ushort* Cb, int M, int N, int K) {
  __shared__ char smem[49152];
  char* As = smem;              // 256 x 64 bf16 = 32 KB
  char* Bs = smem + 32768;      // 128 x 64 bf16 = 16 KB
  int tid = threadIdx.x, lane = tid & 63, w = tid >> 6;
  int nbn = N >> 7;
  int per = gridDim.x >> 3;
  int gl = (blockIdx.x & 7) * per + (blockIdx.x >> 3);
  int bm = gl / nbn, bn = gl % nbn;
  int wr = w >> 1, wc = w & 1;           // 4x2 wave grid, 64x64 per wave
  int g = lane >> 4, r = lane & 15;
  f32x4 acc[4][4] = {};
  for (int ko = 0; ko < K; ko += 64) {
    __syncthreads();
    #pragma unroll
    for (int c = 0; c < 4; ++c) {        // A: 2048 chunks of 16B
      int chunk = c * 512 + tid;
      int row = chunk >> 3;
      int kbs = ((chunk & 7) << 4) ^ ((row & 7) << 4);
      int ar = bm * 256 + row; ar = ar < M ? ar : M - 1;
      const char* gA = (const char*)(A + (size_t)ar * K + ko) + kbs;
      __builtin_amdgcn_global_load_lds((const __attribute__((address_space(1))) void*)gA,
                                       (__attribute__((address_space(3))) void*)(As + c * 8192 + w * 1024),
                                       16, 0, 0);
    }
    #pragma unroll
    for (int c = 0; c < 2; ++c) {        // B: 1024 chunks of 16B
      int chunk = c * 512 + tid;
      int row = chunk >> 3;
      int kbs = ((chunk & 7) << 4) ^ ((row & 7) << 4);
      const char* gB = (const char*)(Bw + (size_t)(bn * 128 + row) * K + ko) + kbs;
      __builtin_amdgcn_global_load_lds((const __attribute__((address_space(1))) void*)gB,
                                       (__attribute__((address_space(3))) void*)(Bs + c * 8192 + w * 1024),
                                       16, 0, 0);
    }
    __syncthreads();
    #pragma unroll
    for (int kk = 0; kk < 2; ++kk) {
      s16x8 af[4], bf[4];
      #pragma unroll
      for (int mt = 0; mt < 4; ++mt) {
        int row = wr * 64 + mt * 16 + r;
        int kb = (kk * 64 + g * 16) ^ ((row & 7) << 4);
        af[mt] = *(const s16x8*)(As + row * 128 + kb);
      }
      #pragma unroll
      for (int nt = 0; nt < 4; ++nt) {
        int row = wc * 64 + nt * 16 + r;
        int kb = (kk * 64 + g * 16) ^ ((row & 7) << 4);
        bf[nt] = *(const s16x8*)(Bs + row * 128 + kb);
      }
      #pragma unroll
      for (int mt = 0; mt < 4; ++mt)
        #pragma unroll
        for (int nt = 0; nt < 4; ++nt)
          acc[mt][nt] = __builtin_amdgcn_mfma_f32_16x16x32_bf16(af[mt], bf[nt], acc[mt][nt], 0, 0, 0);
    }
  }
  #pragma unroll
  for (int nt = 0; nt < 4; ++nt) {
    int col = bn * 128 + wc * 64 + nt * 16 + r;
    float bvv = bias[col];
    float sc = (col < 1024) ? SCALE2 : 1.0f;   // fold attention scale into Q (and qpos)
    #pragma unroll
    for (int mt = 0; mt < 4; ++mt) {
      int row0 = bm * 256 + wr * 64 + mt * 16 + g * 4;
      #pragma unroll
      for (int i = 0; i < 4; ++i) {
        int row = row0 + i;
        if (row < M) Cb[(size_t)row * N + col] = f2bf((acc[mt][nt][i] + bvv) * sc);
      }
    }
  }
}

// ---------------- output GEMM: 128x128 tile, split-K=2, bf16 partials --------------------
__global__ __launch_bounds__(256) void k_gemm_sk(const ushort* A, const ushort* Bw, const float* bias,
                                                 ushort* C0, ushort* C1) {
  const int N = 1024, K = 1024;
  __shared__ char smem[32768];
  char* As = smem;
  char* Bs = smem + 16384;
  int tid = threadIdx.x, lane = tid & 63, w = tid >> 6;
  int per = gridDim.x >> 3;
  int gl = (blockIdx.x & 7) * per + (blockIdx.x >> 3);
  int bn = gl & 7, ks = (gl >> 3) & 1, bm = gl >> 4;
  int wr = w >> 1, wc = w & 1;
  int g = lane >> 4, r = lane & 15;
  f32x4 acc[4][4] = {};
  for (int ko = ks * 512; ko < ks * 512 + 512; ko += 64) {
    __syncthreads();
    #pragma unroll
    for (int c = 0; c < 4; ++c) {
      int chunk = c * 256 + tid;
      int row = chunk >> 3;
      int kbs = ((chunk & 7) << 4) ^ ((row & 7) << 4);
      const char* gA = (const char*)(A + (size_t)(bm * 128 + row) * K + ko) + kbs;
      const char* gB = (const char*)(Bw + (size_t)(bn * 128 + row) * K + ko) + kbs;
      __builtin_amdgcn_global_load_lds((const __attribute__((address_space(1))) void*)gA,
                                       (__attribute__((address_space(3))) void*)(As + c * 4096 + w * 1024),
                                       16, 0, 0);
      __builtin_amdgcn_global_load_lds((const __attribute__((address_space(1))) void*)gB,
                                       (__attribute__((address_space(3))) void*)(Bs + c * 4096 + w * 1024),
                                       16, 0, 0);
    }
    __syncthreads();
    #pragma unroll
    for (int kk = 0; kk < 2; ++kk) {
      s16x8 af[4], bf[4];
      #pragma unroll
      for (int mt = 0; mt < 4; ++mt) {
        int row = wr * 64 + mt * 16 + r;
        int kb = (kk * 64 + g * 16) ^ ((row & 7) << 4);
        af[mt] = *(const s16x8*)(As + row * 128 + kb);
      }
      #pragma unroll
      for (int nt = 0; nt < 4; ++nt) {
        int row = wc * 64 + nt * 16 + r;
        int kb = (kk * 64 + g * 16) ^ ((row & 7) << 4);
        bf[nt] = *(const s16x8*)(Bs + row * 128 + kb);
      }
      #pragma unroll
      for (int mt = 0; mt < 4; ++mt)
        #pragma unroll
        for (int nt = 0; nt < 4; ++nt)
          acc[mt][nt] = __builtin_amdgcn_mfma_f32_16x16x32_bf16(af[mt], bf[nt], acc[mt][nt], 0, 0, 0);
    }
  }
  ushort* C = ks ? C1 : C0;
  #pragma unroll
  for (int nt = 0; nt < 4; ++nt) {
    int col = bn * 128 + wc * 64 + nt * 16 + r;
    float bvv = ks ? 0.0f : bias[col];
    #pragma unroll
    for (int mt = 0; mt < 4; ++mt) {
      int row0 = bm * 128 + wr * 64 + mt * 16 + g * 4;
      #pragma unroll
      for (int i = 0; i < 4; ++i)
        C[(size_t)(row0 + i) * N + col] = f2bf(acc[mt][nt][i] + bvv);
    }
  }
}

// ---------------- positional score tables (bf16, scale inherited from Q, mask in pk) -----
__global__ __launch_bounds__(256) void k_pos(const ushort* qkv, const ushort* mask01,
                                             ushort* qp, ushort* pk) {
  int bh = blockIdx.x;
  int b = bh >> 4, h = bh & 15;
  int tid = threadIdx.x, lane = tid & 63, w = tid >> 6;
  int g = lane >> 4, r = lane & 15;
  __shared__ ushort mb[512];
  for (int i = tid; i < 512; i += 256) mb[i] = mask01[b * SEQ + i];
  __syncthreads();
  s16x8 bkp[4][2], bqp[4][2];   // kpos / qpos B-fragments (t = nt*16+r)
  #pragma unroll
  for (int nt = 0; nt < 4; ++nt)
    #pragma unroll
    for (int kk = 0; kk < 2; ++kk) {
      size_t rowp = (size_t)(NROWS + nt * 16 + r);
      int colq = h * 64 + kk * 32 + g * 8;
      bqp[nt][kk] = *(const s16x8*)(qkv + rowp * NQKV + colq);          // qpos (pre-scaled)
      bkp[nt][kk] = *(const s16x8*)(qkv + rowp * NQKV + 1024 + colq);   // kpos (unscaled)
    }
  for (int cc = 0; cc < 8; ++cc) {
    int rowbase = cc * 64 + w * 16;
    s16x8 aq[2], ak[2];
    #pragma unroll
    for (int kk = 0; kk < 2; ++kk) {
      size_t rowq = (size_t)((rowbase + r) * 16 + b);
      int colq = h * 64 + kk * 32 + g * 8;
      aq[kk] = *(const s16x8*)(qkv + rowq * NQKV + colq);               // q (pre-scaled)
      ak[kk] = *(const s16x8*)(qkv + rowq * NQKV + 1024 + colq);        // k (unscaled)
    }
    f32x4 accq[4] = {}, acck[4] = {};
    #pragma unroll
    for (int kk = 0; kk < 2; ++kk)
      #pragma unroll
      for (int nt = 0; nt < 4; ++nt) {
        accq[nt] = __builtin_amdgcn_mfma_f32_16x16x32_bf16(aq[kk], bkp[nt][kk], accq[nt], 0, 0, 0);
        acck[nt] = __builtin_amdgcn_mfma_f32_16x16x32_bf16(ak[kk], bqp[nt][kk], acck[nt], 0, 0, 0);
      }
    #pragma unroll
    for (int nt = 0; nt < 4; ++nt)
      #pragma unroll
      for (int i = 0; i < 4; ++i) {
        int q = rowbase + g * 4 + i;
        int t = nt * 16 + r;
        float biasv = mb[q] ? -1e9f : 0.0f;          // key-mask baked into pk rows
        qp[(size_t)bh * SEQ * 64 + q * 64 + t] = f2bf(accq[nt][i]);
        pk[(size_t)bh * SEQ * 64 + q * 64 + t] = f2bf(acck[nt][i] + biasv);
      }
  }
}

// ---------------- V transpose + K repack (pure copies): vt[b,h,d,l], kc[b,h,l,d] ---------
__global__ __launch_bounds__(256) void k_vt(const ushort* qkv, ushort* vt, ushort* kc) {
  int bid = blockIdx.x;
  int bh = bid >> 3, lt = bid & 7;
  int b = bh >> 4, h = bh & 15;
  __shared__ ushort tile[64][72];
  int tid = threadIdx.x;
  #pragma unroll
  for (int c = 0; c < 2; ++c) {
    int e = (c * 256 + tid) * 8;
    int l = e >> 6, d0 = e & 63;
    size_t row = (size_t)((lt * 64 + l) * 16 + b);
    s16x8 kv = *(const s16x8*)(qkv + row * NQKV + 1024 + h * 64 + d0);
    *(s16x8*)(kc + ((size_t)bh * SEQ + lt * 64 + l) * 64 + d0) = kv;   // contiguous K rows
    *(s16x8*)&tile[l][d0] = *(const s16x8*)(qkv + row * NQKV + 2048 + h * 64 + d0);
  }
  __syncthreads();
  #pragma unroll
  for (int c = 0; c < 2; ++c) {
    int e = (c * 256 + tid) * 8;
    int d = e >> 6, l0 = e & 63;
    ushort tmp[8];
    #pragma unroll
    for (int j = 0; j < 8; ++j) tmp[j] = tile[l0 + j][d];
    *(s16x8*)(vt + (size_t)(bh * 64 + d) * SEQ + lt * 64 + l0) = *(s16x8*)tmp;
  }
}

// ---------------- fused attention: BARRIER-FREE main loop (R11 structure, kt unroll 2) ---
// Block = (bh, q-half): pk table for ALL 512 k + qp for 256 q staged ONCE (123.9 KB LDS);
// K/V fragments read directly from global (kc/vt, L2-resident, shared by all 8 waves).
// Main loop has ZERO __syncthreads(); unroll 2 lets the scheduler hoist kt+1's K/V loads
// into kt's softmax/PV window (1 block/CU -> 2 waves/SIMD -> 256-VGPR budget, no spill).
__global__ __launch_bounds__(512) void k_attn(const ushort* qkv, const ushort* qp_all, const ushort* pk_all,
                                              const ushort* kc, const ushort* vt,
                                              const int* idx_tab, ushort* ctx) {
  int bid = blockIdx.x;
  int slot = bid >> 3;
  int bh = (bid & 7) * 32 + (slot >> 1);   // both q-halves of a bh on one XCD
  int qh = slot & 1;                       // which 256-row q half
  int b = bh >> 4, h = bh & 15;
  int tid = threadIdx.x, lane = tid & 63, w = tid >> 6;
  int g = lane >> 4, r = lane & 15;

  __shared__ ushort pk_f[512][68];   // 69,632 B  full-k pk table
  __shared__ ushort qp_s[256][68];   // 34,816 B  this half's qp rows
  __shared__ ushort p_s[8][16][68];  // 17,408 B  per-wave P staging (stride 68: conflict-free)
  __shared__ ushort idx_s[1024];     //  2,048 B  -> total 123,904 B

  const ushort* qpsrc = qp_all + (size_t)bh * SEQ * 64 + (size_t)qh * 256 * 64;
  const ushort* pksrc = pk_all + (size_t)bh * SEQ * 64;
  const char*   kcb   = (const char*)(kc + (size_t)bh * SEQ * 64);   // [l][d] 128B rows

  // ---- prologue: stage qp(256 rows), pk(512 rows), idx; load aq; ONE barrier ----
  #pragma unroll
  for (int c = 0; c < 4; ++c) {            // qp: 2048 chunks of 8 u16
    int chunk = c * 512 + tid;
    int row = chunk >> 3, col8 = (chunk & 7) * 8;
    s16x8 v = *(const s16x8*)(qpsrc + (size_t)row * 64 + col8);
    u16x4 lo = { (ushort)v[0], (ushort)v[1], (ushort)v[2], (ushort)v[3] };
    u16x4 hi = { (ushort)v[4], (ushort)v[5], (ushort)v[6], (ushort)v[7] };
    *(u16x4*)&qp_s[row][col8] = lo;
    *(u16x4*)&qp_s[row][col8 + 4] = hi;
  }
  #pragma unroll
  for (int c = 0; c < 8; ++c) {            // pk: 4096 chunks of 8 u16
    int chunk = c * 512 + tid;
    int row = chunk >> 3, col8 = (chunk & 7) * 8;
    s16x8 v = *(const s16x8*)(pksrc + (size_t)row * 64 + col8);
    u16x4 lo = { (ushort)v[0], (ushort)v[1], (ushort)v[2], (ushort)v[3] };
    u16x4 hi = { (ushort)v[4], (ushort)v[5], (ushort)v[6], (ushort)v[7] };
    *(u16x4*)&pk_f[row][col8] = lo;
    *(u16x4*)&pk_f[row][col8 + 4] = hi;
  }
  for (int i = tid; i < 1023; i += 512) idx_s[i] = (ushort)idx_tab[i];
  s16x8 aq[2][2];                          // [qs][kk] Q fragments (pre-scaled by SCALE2)
  #pragma unroll
  for (int qs = 0; qs < 2; ++qs)
    #pragma unroll
    for (int kk = 0; kk < 2; ++kk) {
      int qglob = qh * 256 + qs * 128 + w * 16 + r;
      aq[qs][kk] = *(const s16x8*)(qkv + ((size_t)qglob * 16 + b) * NQKV + h * 64 + kk * 32 + g * 8);
    }
  __syncthreads();   // the ONLY barrier

  float m_i[2] = { -3e38f, -3e38f }, l_i[2] = { 0.0f, 0.0f };
  f32x4 o_acc[2][4] = {};

  #pragma unroll 2
  for (int kt = 0; kt < 8; ++kt) {
    // K and V fragments straight from global (L2-shared across the block's 8 waves)
    s16x8 kf[4][2], vf[2][4];
    #pragma unroll
    for (int nt = 0; nt < 4; ++nt)
      #pragma unroll
      for (int kk = 0; kk < 2; ++kk)
        kf[nt][kk] = *(const s16x8*)(kcb + (size_t)(kt * 64 + nt * 16 + r) * 128 + kk * 64 + g * 16);
    #pragma unroll
    for (int kk = 0; kk < 2; ++kk)
      #pragma unroll
      for (int nt = 0; nt < 4; ++nt)
        vf[kk][nt] = *(const s16x8*)(vt + (size_t)(bh * 64 + nt * 16 + r) * SEQ + kt * 64 + kk * 32 + g * 8);

    #pragma unroll
    for (int qs = 0; qs < 2; ++qs) {
      // ---- swapped QK^T: lane holds S^T for q = r, k = nt*16+g*4+i ----
      f32x4 s[4];
      __builtin_amdgcn_s_setprio(1);
      #pragma unroll
      for (int nt = 0; nt < 4; ++nt) {
        f32x4 a = {};
        #pragma unroll
        for (int kk = 0; kk < 2; ++kk)
          a = __builtin_amdgcn_mfma_f32_16x16x32_bf16(kf[nt][kk], aq[qs][kk], a, 0, 0, 0);   // A=K, B=Q
        s[nt] = a;
      }
      __builtin_amdgcn_s_setprio(0);

      // ---- gather: v = c2c + qp_s[q][t] + pk_f[k][t]  (scale pre-folded, mask in pk) ----
      const ushort* qprow = &qp_s[qs * 128 + w * 16 + r][0];
      const int qg511 = qh * 256 + qs * 128 + w * 16 + r + 511;
      float m_loc = -3e38f;
      #pragma unroll
      for (int nt = 0; nt < 4; ++nt) {
        #pragma unroll
        for (int i = 0; i < 4; ++i) {
          int kg = kt * 64 + nt * 16 + g * 4 + i;
          int t = idx_s[qg511 - kg];
          float v = s[nt][i] + bf2f(qprow[t]) + bf2f(pk_f[kg][t]);
          s[nt][i] = v;
          m_loc = fmaxf(m_loc, v);
        }
      }

      // ---- row max across the 4 g-lanes holding q = r ----
      float mx = fmaxf(m_loc, __shfl_xor(m_loc, 16));
      mx = fmaxf(mx, __shfl_xor(mx, 32));

      // ---- T13 defer-rescale (base-2 threshold 8) ----
      if (__any(mx > m_i[qs] + 8.0f)) {
        float mnew = fmaxf(m_i[qs], mx);
        float rs = exp2f(m_i[qs] - mnew);
        m_i[qs] = mnew;
        l_i[qs] *= rs;
        float rsb[4];
        #pragma unroll
        for (int i = 0; i < 4; ++i) rsb[i] = __shfl(rs, g * 4 + i);   // rs for q = g*4+i
        #pragma unroll
        for (int nt = 0; nt < 4; ++nt)
          #pragma unroll
          for (int i = 0; i < 4; ++i) o_acc[qs][nt][i] *= rsb[i];
      }

      // ---- exp2 + P pack (b64 LDS writes), psum ----
      float psum = 0.0f;
      #pragma unroll
      for (int nt = 0; nt < 4; ++nt) {
        u16x4 pk4;
        #pragma unroll
        for (int i = 0; i < 4; ++i) {
          float pe = exp2f(s[nt][i] - m_i[qs]);   // masked: huge negative -> exact 0
          psum += pe;
          pk4[i] = f2bf(pe);
        }
        *(u16x4*)&p_s[w][r][nt * 16 + g * 4] = pk4;
      }
      psum += __shfl_xor(psum, 16);
      psum += __shfl_xor(psum, 32);
      l_i[qs] += psum;

      // ---- PV (2 x b64 p reads; per-wave roundtrip ordered by lgkmcnt) ----
      __builtin_amdgcn_s_setprio(1);
      #pragma unroll
      for (int kk = 0; kk < 2; ++kk) {
        u16x4 lo = *(const u16x4*)&p_s[w][r][kk * 32 + g * 8];
        u16x4 hi = *(const u16x4*)&p_s[w][r][kk * 32 + g * 8 + 4];
        s16x8 pa = { (short)lo[0], (short)lo[1], (short)lo[2], (short)lo[3],
                     (short)hi[0], (short)hi[1], (short)hi[2], (short)hi[3] };
        #pragma unroll
        for (int nt = 0; nt < 4; ++nt)
          o_acc[qs][nt] = __builtin_amdgcn_mfma_f32_16x16x32_bf16(pa, vf[kk][nt], o_acc[qs][nt], 0, 0, 0);
      }
      __builtin_amdgcn_s_setprio(0);
    }
  }

  #pragma unroll
  for (int qs = 0; qs < 2; ++qs) {
    float lb[4];
    #pragma unroll
    for (int i = 0; i < 4; ++i) lb[i] = __shfl(l_i[qs], g * 4 + i);   // l for q = g*4+i
    #pragma unroll
    for (int i = 0; i < 4; ++i) {
      float inv = lb[i] > 0.0f ? 1.0f / lb[i] : 0.0f;
      int lq = qh * 256 + qs * 128 + w * 16 + g * 4 + i;
      size_t rowc = (size_t)(lq * 16 + b);
      #pragma unroll
      for (int nt = 0; nt < 4; ++nt)
        ctx[rowc * HID + h * 64 + nt * 16 + r] = f2bf(o_acc[qs][nt][i] * inv);
    }
  }
}

// ---------------- LN2 (affine), two bf16 partials in -> f32 out --------------------------
__global__ __launch_bounds__(256) void k_ln2(const ushort* t0, const ushort* t1,
                                             const float* gamma, const float* beta, float* out) {
  int row = blockIdx.x, tid = threadIdx.x;
  __shared__ float red[8];
  u16x4 xa = *(const u16x4*)(t0 + (size_t)row * HID + tid * 4);
  u16x4 xb = *(const u16x4*)(t1 + (size_t)row * HID + tid * 4);
  float x[4];
  #pragma unroll
  for (int j = 0; j < 4; ++j) x[j] = bf2f(xa[j]) + bf2f(xb[j]);
  float s = x[0] + x[1] + x[2] + x[3];
  #pragma unroll
  for (int m = 1; m < 64; m <<= 1) s += __shfl_xor(s, m);
  if ((tid & 63) == 0) red[tid >> 6] = s;
  __syncthreads();
  float mean = (red[0] + red[1] + red[2] + red[3]) * (1.0f / HID);
  float d[4]; float sq = 0.0f;
  #pragma unroll
  for (int j = 0; j < 4; ++j) { d[j] = x[j] - mean; sq += d[j] * d[j]; }
  #pragma unroll
  for (int m = 1; m < 64; m <<= 1) sq += __shfl_xor(sq, m);
  __syncthreads();
  if ((tid & 63) == 0) red[4 + (tid >> 6)] = sq;
  __syncthreads();
  float var = (red[4] + red[5] + red[6] + red[7]) * (1.0f / HID);
  float rs = rsqrtf(var + LNEPS);
  f32x4 o;
  #pragma unroll
  for (int j = 0; j < 4; ++j) o[j] = d[j] * rs * gamma[tid * 4 + j] + beta[tid * 4 + j];
  *(f32x4*)(out + (size_t)row * HID + tid * 4) = o;
}

// ---------------- launch -----------------------------------------------------------------
extern "C" void kernel_launch(void* const* d_in, const int* in_sizes, int n_in,
                              void* d_out, int out_size, void* d_ws, size_t ws_size,
                              hipStream_t stream) {
  (void)in_sizes; (void)n_in; (void)out_size; (void)ws_size;
  const float* hid  = (const float*)d_in[0];
  const void*  mask = d_in[1];
  const float* rel  = (const float*)d_in[2];
  const float* wqk  = (const float*)d_in[3];
  const float* bqk  = (const float*)d_in[4];
  const float* wv   = (const float*)d_in[5];
  const float* bv   = (const float*)d_in[6];
  const float* wo   = (const float*)d_in[7];
  const float* bo   = (const float*)d_in[8];
  const float* ln_g = (const float*)d_in[9];
  const float* ln_b = (const float*)d_in[10];

  char* ws = (char*)d_ws;
  ushort* wcat     = (ushort*)(ws);                 //  6,291,456
  ushort* wo_b     = (ushort*)(ws + 6291456);       //  2,097,152
  float*  bcat     = (float*) (ws + 8388608);       //     12,288
  ushort* mask01   = (ushort*)(ws + 8400896);       //     16,384 (region 32,768)
  int*    idx_tab  = (int*)   (ws + 8433664);       //      4,096
  ushort* h_ext    = (ushort*)(ws + 8437760);       // 17,039,360  (reused as ctx)
  ushort* qkv      = (ushort*)(ws + 25477120);      // 51,118,080
  ushort* qp_b     = (ushort*)(ws + 76595200);      // 16,777,216 (bf16, scale inherited)
  ushort* pk_b     = (ushort*)(ws + 93372416);      // 16,777,216 (bf16, scale + mask)
  ushort* vt       = (ushort*)(ws + 110149632);     // 16,777,216
  char*   tmpr     = (ws + 126926848);              // 33,554,432 region
  ushort* ctx = h_ext;
  ushort* kc   = (ushort*)tmpr;                     // dead once k_attn finishes
  ushort* tmp0 = (ushort*)tmpr;                     // split-K partial 0 (16,777,216)
  ushort* tmp1 = (ushort*)(tmpr + 16777216);        // split-K partial 1 (16,777,216)

  k_prep<<<1, 256, 0, stream>>>(mask, bqk, bv, mask01, idx_tab, bcat);
  k_convert<<<4096, 256, 0, stream>>>(wqk, wv, wo, wcat, wo_b);
  k_ln1<<<MEXT, 256, 0, stream>>>(hid, rel, h_ext);
  k_gemm256<<<33 * (NQKV / 128), 512, 0, stream>>>(h_ext, wcat, bcat, qkv, MEXT, NQKV, 1024);
  k_pos<<<256, 256, 0, stream>>>(qkv, mask01, qp_b, pk_b);
  k_vt<<<2048, 256, 0, stream>>>(qkv, vt, kc);
  k_attn<<<512, 512, 0, stream>>>(qkv, qp_b, pk_b, kc, vt, idx_tab, ctx);
  k_gemm_sk<<<1024, 256, 0, stream>>>(ctx, wo_b, bo, tmp0, tmp1);
  k_ln2<<<NROWS, 256, 0, stream>>>(tmp0, tmp1, ln_g, ln_b, (float*)d_out);
}

// Round 15
// 247.832 us; speedup vs baseline: 1.2137x; 1.0074x over previous
//
#include <hip/hip_runtime.h>
#include <hip/hip_bf16.h>

#define HID 1024
#define HEADS 16
#define HEAD 64
#define RELN 63
#define SEQ 512
#define BATCH 16
#define NROWS (SEQ*BATCH)      // 8192
#define MEXT 8320              // 8192 + 63, padded to 65*128
#define NQKV 3072
#define LNEPS 1e-7f
// 1/sqrt(3*64) * log2(e): folded into Q at the QKV-GEMM epilogue (base-2 domain)
#define SCALE2 (0.07216878364870323f * 1.4426950408889634f)

typedef __attribute__((ext_vector_type(4))) float  f32x4;
typedef __attribute__((ext_vector_type(8))) short  s16x8;
typedef __attribute__((ext_vector_type(4))) ushort u16x4;

static __device__ __forceinline__ ushort f2bf(float f) {
  __hip_bfloat16 h = __float2bfloat16(f);        // native RNE cvt
  return *reinterpret_cast<ushort*>(&h);
}
static __device__ __forceinline__ float bf2f(ushort u) {
  union { unsigned u; float f; } v; v.u = ((unsigned)u) << 16;
  return v.f;
}

// ---------------- fused: weight f32->bf16 convert (blocks 0..4095) + prep (block 4096) ---
__global__ __launch_bounds__(256) void k_conv_prep(const float* wqk, const float* wv, const float* wo,
                                                   ushort* wcat, ushort* wo_b,
                                                   const void* mask_raw, const float* bqk, const float* bv,
                                                   ushort* mask01, int* idx_tab, float* bcat) {
  int bid = blockIdx.x, tid = threadIdx.x;
  if (bid < 4096) {
    int c = bid * 256 + tid;    // 1,048,576 chunks of 4 elems
    f32x4 x; ushort* dst;
    if (c < 524288)      { x = *(const f32x4*)(wqk + (size_t)c * 4);            dst = wcat + (size_t)c * 4; }
    else if (c < 786432) { x = *(const f32x4*)(wv  + (size_t)(c - 524288) * 4); dst = wcat + (size_t)c * 4; }
    else                 { x = *(const f32x4*)(wo  + (size_t)(c - 786432) * 4); dst = wo_b + (size_t)(c - 786432) * 4; }
    u16x4 o = { f2bf(x[0]), f2bf(x[1]), f2bf(x[2]), f2bf(x[3]) };
    *(u16x4*)dst = o;
    return;
  }
  // ---- prep (one block) ----
  __shared__ int s_isbool;
  if (tid == 0) s_isbool = 0;
  __syncthreads();
  const unsigned* mu = (const unsigned*)mask_raw;
  int bad = 0;
  for (int i = tid; i < 2048; i += 256) if (mu[i] > 1u) bad = 1;
  if (bad) s_isbool = 1;              // benign race: any writer writes 1
  __syncthreads();
  int isbool = s_isbool;
  const unsigned char* m8 = (const unsigned char*)mask_raw;
  const int* m32 = (const int*)mask_raw;
  for (int i = tid; i < BATCH*SEQ; i += 256) {
    int m = isbool ? (int)m8[i] : m32[i];
    mask01[i] = m ? 1 : 0;
  }
  for (int i = tid; i < 1023; i += 256) {
    int r = i - 511;
    int a = r < 0 ? -r : r;
    int absp = (a < 16) ? 15 : (a < 511 ? a : 511);
    int idx;
    if (absp <= 16) idx = 31 + r;
    else {
      float v = logf((float)absp / 16.0f) / logf(511.0f / 16.0f) * 15.0f;
      int lp = (int)ceilf(v) + 16;
      idx = 31 + (r > 0 ? lp : -lp);
    }
    idx_tab[i] = idx;
  }
  for (int i = tid; i < 2048; i += 256) bcat[i] = bqk[i];
  for (int i = tid; i < 1024; i += 256) bcat[2048 + i] = bv[i];
}

// ---------------- LN1 (no affine) -> bf16, plus rel-embedding rows + zero pad ------------
__global__ __launch_bounds__(256) void k_ln1(const float* hid, const float* rel, ushort* h_ext) {
  int row = blockIdx.x, tid = threadIdx.x;
  __shared__ float red[8];
  if (row < NROWS) {
    const float* src = hid + (size_t)row * HID;
    f32x4 x = *(const f32x4*)(src + tid * 4);
    float s = x[0] + x[1] + x[2] + x[3];
    #pragma unroll
    for (int m = 1; m < 64; m <<= 1) s += __shfl_xor(s, m);
    if ((tid & 63) == 0) red[tid >> 6] = s;
    __syncthreads();
    float mean = (red[0] + red[1] + red[2] + red[3]) * (1.0f / HID);
    float d0 = x[0] - mean, d1 = x[1] - mean, d2 = x[2] - mean, d3 = x[3] - mean;
    float sq = d0*d0 + d1*d1 + d2*d2 + d3*d3;
    #pragma unroll
    for (int m = 1; m < 64; m <<= 1) sq += __shfl_xor(sq, m);
    __syncthreads();
    if ((tid & 63) == 0) red[4 + (tid >> 6)] = sq;
    __syncthreads();
    float var = (red[4] + red[5] + red[6] + red[7]) * (1.0f / HID);
    float rs = rsqrtf(var + LNEPS);
    u16x4 o = { f2bf(d0*rs), f2bf(d1*rs), f2bf(d2*rs), f2bf(d3*rs) };
    *(u16x4*)(h_ext + (size_t)row * HID + tid * 4) = o;
  } else if (row < NROWS + RELN) {
    const float* src = rel + (size_t)(row - NROWS) * HID;
    f32x4 x = *(const f32x4*)(src + tid * 4);
    u16x4 o = { f2bf(x[0]), f2bf(x[1]), f2bf(x[2]), f2bf(x[3]) };
    *(u16x4*)(h_ext + (size_t)row * HID + tid * 4) = o;
  } else {
    u16x4 z = { 0, 0, 0, 0 };
    *(u16x4*)(h_ext + (size_t)row * HID + tid * 4) = z;
  }
}

// ---------------- QKV GEMM: 256x128 tile, 8 waves, BK=64, swizzled global_load_lds -------
// Q columns (col<1024) pre-scaled by SCALE2 at the epilogue (base-2 attention domain).
__global__ __launch_bounds__(512) void k_gemm256(const ushort* A, const ushort* Bw, const float* bias,
                                                 ushort* Cb, int M, int N, int K) {
  __shared__ char smem[49152];
  char* As = smem;              // 256 x 64 bf16 = 32 KB
  char* Bs = smem + 32768;      // 128 x 64 bf16 = 16 KB
  int tid = threadIdx.x, lane = tid & 63, w = tid >> 6;
  int nbn = N >> 7;
  int per = gridDim.x >> 3;
  int gl = (blockIdx.x & 7) * per + (blockIdx.x >> 3);
  int bm = gl / nbn, bn = gl % nbn;
  int wr = w >> 1, wc = w & 1;           // 4x2 wave grid, 64x64 per wave
  int g = lane >> 4, r = lane & 15;
  f32x4 acc[4][4] = {};
  for (int ko = 0; ko < K; ko += 64) {
    __syncthreads();
    #pragma unroll
    for (int c = 0; c < 4; ++c) {        // A: 2048 chunks of 16B
      int chunk = c * 512 + tid;
      int row = chunk >> 3;
      int kbs = ((chunk & 7) << 4) ^ ((row & 7) << 4);
      int ar = bm * 256 + row; ar = ar < M ? ar : M - 1;
      const char* gA = (const char*)(A + (size_t)ar * K + ko) + kbs;
      __builtin_amdgcn_global_load_lds((const __attribute__((address_space(1))) void*)gA,
                                       (__attribute__((address_space(3))) void*)(As + c * 8192 + w * 1024),
                                       16, 0, 0);
    }
    #pragma unroll
    for (int c = 0; c < 2; ++c) {        // B: 1024 chunks of 16B
      int chunk = c * 512 + tid;
      int row = chunk >> 3;
      int kbs = ((chunk & 7) << 4) ^ ((row & 7) << 4);
      const char* gB = (const char*)(Bw + (size_t)(bn * 128 + row) * K + ko) + kbs;
      __builtin_amdgcn_global_load_lds((const __attribute__((address_space(1))) void*)gB,
                                       (__attribute__((address_space(3))) void*)(Bs + c * 8192 + w * 1024),
                                       16, 0, 0);
    }
    __syncthreads();
    #pragma unroll
    for (int kk = 0; kk < 2; ++kk) {
      s16x8 af[4], bf[4];
      #pragma unroll
      for (int mt = 0; mt < 4; ++mt) {
        int row = wr * 64 + mt * 16 + r;
        int kb = (kk * 64 + g * 16) ^ ((row & 7) << 4);
        af[mt] = *(const s16x8*)(As + row * 128 + kb);
      }
      #pragma unroll
      for (int nt = 0; nt < 4; ++nt) {
        int row = wc * 64 + nt * 16 + r;
        int kb = (kk * 64 + g * 16) ^ ((row & 7) << 4);
        bf[nt] = *(const s16x8*)(Bs + row * 128 + kb);
      }
      #pragma unroll
      for (int mt = 0; mt < 4; ++mt)
        #pragma unroll
        for (int nt = 0; nt < 4; ++nt)
          acc[mt][nt] = __builtin_amdgcn_mfma_f32_16x16x32_bf16(af[mt], bf[nt], acc[mt][nt], 0, 0, 0);
    }
  }
  #pragma unroll
  for (int nt = 0; nt < 4; ++nt) {
    int col = bn * 128 + wc * 64 + nt * 16 + r;
    float bvv = bias[col];
    float sc = (col < 1024) ? SCALE2 : 1.0f;   // fold attention scale into Q (and qpos)
    #pragma unroll
    for (int mt = 0; mt < 4; ++mt) {
      int row0 = bm * 256 + wr * 64 + mt * 16 + g * 4;
      #pragma unroll
      for (int i = 0; i < 4; ++i) {
        int row = row0 + i;
        if (row < M) Cb[(size_t)row * N + col] = f2bf((acc[mt][nt][i] + bvv) * sc);
      }
    }
  }
}

// ---------------- output GEMM: 256x128 tile, split-K=2, bf16 partials --------------------
// grid = 32(bm) x 8(bn) x 2(ks) = 512; bm-major under XCD swizzle (A panel shared per chunk).
__global__ __launch_bounds__(512) void k_gemm_sk2(const ushort* A, const ushort* Bw, const float* bias,
                                                  ushort* C0, ushort* C1) {
  const int N = 1024, K = 1024;
  __shared__ char smem[49152];
  char* As = smem;              // 256 x 64 bf16 = 32 KB
  char* Bs = smem + 32768;      // 128 x 64 bf16 = 16 KB
  int tid = threadIdx.x, lane = tid & 63, w = tid >> 6;
  int per = gridDim.x >> 3;
  int gl = (blockIdx.x & 7) * per + (blockIdx.x >> 3);
  int bm = gl >> 4, bn = (gl >> 1) & 7, ks = gl & 1;
  int wr = w >> 1, wc = w & 1;
  int g = lane >> 4, r = lane & 15;
  f32x4 acc[4][4] = {};
  for (int ko = ks * 512; ko < ks * 512 + 512; ko += 64) {
    __syncthreads();
    #pragma unroll
    for (int c = 0; c < 4; ++c) {        // A: 2048 chunks of 16B
      int chunk = c * 512 + tid;
      int row = chunk >> 3;
      int kbs = ((chunk & 7) << 4) ^ ((row & 7) << 4);
      const char* gA = (const char*)(A + (size_t)(bm * 256 + row) * K + ko) + kbs;
      __builtin_amdgcn_global_load_lds((const __attribute__((address_space(1))) void*)gA,
                                       (__attribute__((address_space(3))) void*)(As + c * 8192 + w * 1024),
                                       16, 0, 0);
    }
    #pragma unroll
    for (int c = 0; c < 2; ++c) {        // B: 1024 chunks of 16B
      int chunk = c * 512 + tid;
      int row = chunk >> 3;
      int kbs = ((chunk & 7) << 4) ^ ((row & 7) << 4);
      const char* gB = (const char*)(Bw + (size_t)(bn * 128 + row) * K + ko) + kbs;
      __builtin_amdgcn_global_load_lds((const __attribute__((address_space(1))) void*)gB,
                                       (__attribute__((address_space(3))) void*)(Bs + c * 8192 + w * 1024),
                                       16, 0, 0);
    }
    __syncthreads();
    #pragma unroll
    for (int kk = 0; kk < 2; ++kk) {
      s16x8 af[4], bf[4];
      #pragma unroll
      for (int mt = 0; mt < 4; ++mt) {
        int row = wr * 64 + mt * 16 + r;
        int kb = (kk * 64 + g * 16) ^ ((row & 7) << 4);
        af[mt] = *(const s16x8*)(As + row * 128 + kb);
      }
      #pragma unroll
      for (int nt = 0; nt < 4; ++nt) {
        int row = wc * 64 + nt * 16 + r;
        int kb = (kk * 64 + g * 16) ^ ((row & 7) << 4);
        bf[nt] = *(const s16x8*)(Bs + row * 128 + kb);
      }
      #pragma unroll
      for (int mt = 0; mt < 4; ++mt)
        #pragma unroll
        for (int nt = 0; nt < 4; ++nt)
          acc[mt][nt] = __builtin_amdgcn_mfma_f32_16x16x32_bf16(af[mt], bf[nt], acc[mt][nt], 0, 0, 0);
    }
  }
  ushort* C = ks ? C1 : C0;
  #pragma unroll
  for (int nt = 0; nt < 4; ++nt) {
    int col = bn * 128 + wc * 64 + nt * 16 + r;
    float bvv = ks ? 0.0f : bias[col];
    #pragma unroll
    for (int mt = 0; mt < 4; ++mt) {
      int row0 = bm * 256 + wr * 64 + mt * 16 + g * 4;
      #pragma unroll
      for (int i = 0; i < 4; ++i)
        C[(size_t)(row0 + i) * N + col] = f2bf(acc[mt][nt][i] + bvv);
    }
  }
}

// ---------------- fused: V transpose + K repack (blocks <2048) | pos tables (>=2048) -----
__global__ __launch_bounds__(256) void k_vtpos(const ushort* qkv, const ushort* mask01,
                                               ushort* vt, ushort* kc, ushort* qp, ushort* pk) {
  int bid = blockIdx.x, tid = threadIdx.x;
  if (bid < 2048) {
    // ---- V transpose + K repack: vt[b,h,d,l], kc[b,h,l,d] ----
    int bh = bid >> 3, lt = bid & 7;
    int b = bh >> 4, h = bh & 15;
    __shared__ ushort tile[64][72];
    #pragma unroll
    for (int c = 0; c < 2; ++c) {
      int e = (c * 256 + tid) * 8;
      int l = e >> 6, d0 = e & 63;
      size_t row = (size_t)((lt * 64 + l) * 16 + b);
      s16x8 kv = *(const s16x8*)(qkv + row * NQKV + 1024 + h * 64 + d0);
      *(s16x8*)(kc + ((size_t)bh * SEQ + lt * 64 + l) * 64 + d0) = kv;   // contiguous K rows
      *(s16x8*)&tile[l][d0] = *(const s16x8*)(qkv + row * NQKV + 2048 + h * 64 + d0);
    }
    __syncthreads();
    #pragma unroll
    for (int c = 0; c < 2; ++c) {
      int e = (c * 256 + tid) * 8;
      int d = e >> 6, l0 = e & 63;
      ushort tmp[8];
      #pragma unroll
      for (int j = 0; j < 8; ++j) tmp[j] = tile[l0 + j][d];
      *(s16x8*)(vt + (size_t)(bh * 64 + d) * SEQ + lt * 64 + l0) = *(s16x8*)tmp;
    }
    return;
  }
  // ---- positional score tables (bf16, scale inherited from Q, mask baked into pk) ----
  int bh = bid - 2048;
  int b = bh >> 4, h = bh & 15;
  int lane = tid & 63, w = tid >> 6;
  int g = lane >> 4, r = lane & 15;
  __shared__ ushort mb[512];
  for (int i = tid; i < 512; i += 256) mb[i] = mask01[b * SEQ + i];
  __syncthreads();
  s16x8 bkp[4][2], bqp[4][2];   // kpos / qpos B-fragments (t = nt*16+r)
  #pragma unroll
  for (int nt = 0; nt < 4; ++nt)
    #pragma unroll
    for (int kk = 0; kk < 2; ++kk) {
      size_t rowp = (size_t)(NROWS + nt * 16 + r);
      int colq = h * 64 + kk * 32 + g * 8;
      bqp[nt][kk] = *(const s16x8*)(qkv + rowp * NQKV + colq);          // qpos (pre-scaled)
      bkp[nt][kk] = *(const s16x8*)(qkv + rowp * NQKV + 1024 + colq);   // kpos (unscaled)
    }
  for (int cc = 0; cc < 8; ++cc) {
    int rowbase = cc * 64 + w * 16;
    s16x8 aq[2], ak[2];
    #pragma unroll
    for (int kk = 0; kk < 2; ++kk) {
      size_t rowq = (size_t)((rowbase + r) * 16 + b);
      int colq = h * 64 + kk * 32 + g * 8;
      aq[kk] = *(const s16x8*)(qkv + rowq * NQKV + colq);               // q (pre-scaled)
      ak[kk] = *(const s16x8*)(qkv + rowq * NQKV + 1024 + colq);        // k (unscaled)
    }
    f32x4 accq[4] = {}, acck[4] = {};
    #pragma unroll
    for (int kk = 0; kk < 2; ++kk)
      #pragma unroll
      for (int nt = 0; nt < 4; ++nt) {
        accq[nt] = __builtin_amdgcn_mfma_f32_16x16x32_bf16(aq[kk], bkp[nt][kk], accq[nt], 0, 0, 0);
        acck[nt] = __builtin_amdgcn_mfma_f32_16x16x32_bf16(ak[kk], bqp[nt][kk], acck[nt], 0, 0, 0);
      }
    #pragma unroll
    for (int nt = 0; nt < 4; ++nt)
      #pragma unroll
      for (int i = 0; i < 4; ++i) {
        int q = rowbase + g * 4 + i;
        int t = nt * 16 + r;
        float biasv = mb[q] ? -1e9f : 0.0f;          // key-mask baked into pk rows
        qp[(size_t)bh * SEQ * 64 + q * 64 + t] = f2bf(accq[nt][i]);
        pk[(size_t)bh * SEQ * 64 + q * 64 + t] = f2bf(acck[nt][i] + biasv);
      }
  }
}

// ---------------- fused attention: BARRIER-FREE main loop (R11 structure, kt unroll 2) ---
__global__ __launch_bounds__(512) void k_attn(const ushort* qkv, const ushort* qp_all, const ushort* pk_all,
                                              const ushort* kc, const ushort* vt,
                                              const int* idx_tab, ushort* ctx) {
  int bid = blockIdx.x;
  int slot = bid >> 3;
  int bh = (bid & 7) * 32 + (slot >> 1);   // both q-halves of a bh on one XCD
  int qh = slot & 1;                       // which 256-row q half
  int b = bh >> 4, h = bh & 15;
  int tid = threadIdx.x, lane = tid & 63, w = tid >> 6;
  int g = lane >> 4, r = lane & 15;

  __shared__ ushort pk_f[512][68];   // 69,632 B  full-k pk table
  __shared__ ushort qp_s[256][68];   // 34,816 B  this half's qp rows
  __shared__ ushort p_s[8][16][68];  // 17,408 B  per-wave P staging (stride 68: conflict-free)
  __shared__ ushort idx_s[1024];     //  2,048 B  -> total 123,904 B

  const ushort* qpsrc = qp_all + (size_t)bh * SEQ * 64 + (size_t)qh * 256 * 64;
  const ushort* pksrc = pk_all + (size_t)bh * SEQ * 64;
  const char*   kcb   = (const char*)(kc + (size_t)bh * SEQ * 64);   // [l][d] 128B rows

  // ---- prologue: stage qp(256 rows), pk(512 rows), idx; load aq; ONE barrier ----
  #pragma unroll
  for (int c = 0; c < 4; ++c) {            // qp: 2048 chunks of 8 u16
    int chunk = c * 512 + tid;
    int row = chunk >> 3, col8 = (chunk & 7) * 8;
    s16x8 v = *(const s16x8*)(qpsrc + (size_t)row * 64 + col8);
    u16x4 lo = { (ushort)v[0], (ushort)v[1], (ushort)v[2], (ushort)v[3] };
    u16x4 hi = { (ushort)v[4], (ushort)v[5], (ushort)v[6], (ushort)v[7] };
    *(u16x4*)&qp_s[row][col8] = lo;
    *(u16x4*)&qp_s[row][col8 + 4] = hi;
  }
  #pragma unroll
  for (int c = 0; c < 8; ++c) {            // pk: 4096 chunks of 8 u16
    int chunk = c * 512 + tid;
    int row = chunk >> 3, col8 = (chunk & 7) * 8;
    s16x8 v = *(const s16x8*)(pksrc + (size_t)row * 64 + col8);
    u16x4 lo = { (ushort)v[0], (ushort)v[1], (ushort)v[2], (ushort)v[3] };
    u16x4 hi = { (ushort)v[4], (ushort)v[5], (ushort)v[6], (ushort)v[7] };
    *(u16x4*)&pk_f[row][col8] = lo;
    *(u16x4*)&pk_f[row][col8 + 4] = hi;
  }
  for (int i = tid; i < 1023; i += 512) idx_s[i] = (ushort)idx_tab[i];
  s16x8 aq[2][2];                          // [qs][kk] Q fragments (pre-scaled by SCALE2)
  #pragma unroll
  for (int qs = 0; qs < 2; ++qs)
    #pragma unroll
    for (int kk = 0; kk < 2; ++kk) {
      int qglob = qh * 256 + qs * 128 + w * 16 + r;
      aq[qs][kk] = *(const s16x8*)(qkv + ((size_t)qglob * 16 + b) * NQKV + h * 64 + kk * 32 + g * 8);
    }
  __syncthreads();   // the ONLY barrier

  float m_i[2] = { -3e38f, -3e38f }, l_i[2] = { 0.0f, 0.0f };
  f32x4 o_acc[2][4] = {};

  #pragma unroll 2
  for (int kt = 0; kt < 8; ++kt) {
    // K and V fragments straight from global (L2-shared across the block's 8 waves)
    s16x8 kf[4][2], vf[2][4];
    #pragma unroll
    for (int nt = 0; nt < 4; ++nt)
      #pragma unroll
      for (int kk = 0; kk < 2; ++kk)
        kf[nt][kk] = *(const s16x8*)(kcb + (size_t)(kt * 64 + nt * 16 + r) * 128 + kk * 64 + g * 16);
    #pragma unroll
    for (int kk = 0; kk < 2; ++kk)
      #pragma unroll
      for (int nt = 0; nt < 4; ++nt)
        vf[kk][nt] = *(const s16x8*)(vt + (size_t)(bh * 64 + nt * 16 + r) * SEQ + kt * 64 + kk * 32 + g * 8);

    #pragma unroll
    for (int qs = 0; qs < 2; ++qs) {
      // ---- swapped QK^T: lane holds S^T for q = r, k = nt*16+g*4+i ----
      f32x4 s[4];
      __builtin_amdgcn_s_setprio(1);
      #pragma unroll
      for (int nt = 0; nt < 4; ++nt) {
        f32x4 a = {};
        #pragma unroll
        for (int kk = 0; kk < 2; ++kk)
          a = __builtin_amdgcn_mfma_f32_16x16x32_bf16(kf[nt][kk], aq[qs][kk], a, 0, 0, 0);   // A=K, B=Q
        s[nt] = a;
      }
      __builtin_amdgcn_s_setprio(0);

      // ---- gather: v = c2c + qp_s[q][t] + pk_f[k][t]  (scale pre-folded, mask in pk) ----
      const ushort* qprow = &qp_s[qs * 128 + w * 16 + r][0];
      const int qg511 = qh * 256 + qs * 128 + w * 16 + r + 511;
      float m_loc = -3e38f;
      #pragma unroll
      for (int nt = 0; nt < 4; ++nt) {
        #pragma unroll
        for (int i = 0; i < 4; ++i) {
          int kg = kt * 64 + nt * 16 + g * 4 + i;
          int t = idx_s[qg511 - kg];
          float v = s[nt][i] + bf2f(qprow[t]) + bf2f(pk_f[kg][t]);
          s[nt][i] = v;
          m_loc = fmaxf(m_loc, v);
        }
      }

      // ---- row max across the 4 g-lanes holding q = r ----
      float mx = fmaxf(m_loc, __shfl_xor(m_loc, 16));
      mx = fmaxf(mx, __shfl_xor(mx, 32));

      // ---- T13 defer-rescale (base-2 threshold 8) ----
      if (__any(mx > m_i[qs] + 8.0f)) {
        float mnew = fmaxf(m_i[qs], mx);
        float rs = exp2f(m_i[qs] - mnew);
        m_i[qs] = mnew;
        l_i[qs] *= rs;
        float rsb[4];
        #pragma unroll
        for (int i = 0; i < 4; ++i) rsb[i] = __shfl(rs, g * 4 + i);   // rs for q = g*4+i
        #pragma unroll
        for (int nt = 0; nt < 4; ++nt)
          #pragma unroll
          for (int i = 0; i < 4; ++i) o_acc[qs][nt][i] *= rsb[i];
      }

      // ---- exp2 + P pack (b64 LDS writes), psum ----
      float psum = 0.0f;
      #pragma unroll
      for (int nt = 0; nt < 4; ++nt) {
        u16x4 pk4;
        #pragma unroll
        for (int i = 0; i < 4; ++i) {
          float pe = exp2f(s[nt][i] - m_i[qs]);   // masked: huge negative -> exact 0
          psum += pe;
          pk4[i] = f2bf(pe);
        }
        *(u16x4*)&p_s[w][r][nt * 16 + g * 4] = pk4;
      }
      psum += __shfl_xor(psum, 16);
      psum += __shfl_xor(psum, 32);
      l_i[qs] += psum;

      // ---- PV (2 x b64 p reads; per-wave roundtrip ordered by lgkmcnt) ----
      __builtin_amdgcn_s_setprio(1);
      #pragma unroll
      for (int kk = 0; kk < 2; ++kk) {
        u16x4 lo = *(const u16x4*)&p_s[w][r][kk * 32 + g * 8];
        u16x4 hi = *(const u16x4*)&p_s[w][r][kk * 32 + g * 8 + 4];
        s16x8 pa = { (short)lo[0], (short)lo[1], (short)lo[2], (short)lo[3],
                     (short)hi[0], (short)hi[1], (short)hi[2], (short)hi[3] };
        #pragma unroll
        for (int nt = 0; nt < 4; ++nt)
          o_acc[qs][nt] = __builtin_amdgcn_mfma_f32_16x16x32_bf16(pa, vf[kk][nt], o_acc[qs][nt], 0, 0, 0);
      }
      __builtin_amdgcn_s_setprio(0);
    }
  }

  #pragma unroll
  for (int qs = 0; qs < 2; ++qs) {
    float lb[4];
    #pragma unroll
    for (int i = 0; i < 4; ++i) lb[i] = __shfl(l_i[qs], g * 4 + i);   // l for q = g*4+i
    #pragma unroll
    for (int i = 0; i < 4; ++i) {
      float inv = lb[i] > 0.0f ? 1.0f / lb[i] : 0.0f;
      int lq = qh * 256 + qs * 128 + w * 16 + g * 4 + i;
      size_t rowc = (size_t)(lq * 16 + b);
      #pragma unroll
      for (int nt = 0; nt < 4; ++nt)
        ctx[rowc * HID + h * 64 + nt * 16 + r] = f2bf(o_acc[qs][nt][i] * inv);
    }
  }
}

// ---------------- LN2 (affine), two bf16 partials in -> f32 out --------------------------
__global__ __launch_bounds__(256) void k_ln2(const ushort* t0, const ushort* t1,
                                             const float* gamma, const float* beta, float* out) {
  int row = blockIdx.x, tid = threadIdx.x;
  __shared__ float red[8];
  u16x4 xa = *(const u16x4*)(t0 + (size_t)row * HID + tid * 4);
  u16x4 xb = *(const u16x4*)(t1 + (size_t)row * HID + tid * 4);
  float x[4];
  #pragma unroll
  for (int j = 0; j < 4; ++j) x[j] = bf2f(xa[j]) + bf2f(xb[j]);
  float s = x[0] + x[1] + x[2] + x[3];
  #pragma unroll
  for (int m = 1; m < 64; m <<= 1) s += __shfl_xor(s, m);
  if ((tid & 63) == 0) red[tid >> 6] = s;
  __syncthreads();
  float mean = (red[0] + red[1] + red[2] + red[3]) * (1.0f / HID);
  float d[4]; float sq = 0.0f;
  #pragma unroll
  for (int j = 0; j < 4; ++j) { d[j] = x[j] - mean; sq += d[j] * d[j]; }
  #pragma unroll
  for (int m = 1; m < 64; m <<= 1) sq += __shfl_xor(sq, m);
  __syncthreads();
  if ((tid & 63) == 0) red[4 + (tid >> 6)] = sq;
  __syncthreads();
  float var = (red[4] + red[5] + red[6] + red[7]) * (1.0f / HID);
  float rs = rsqrtf(var + LNEPS);
  f32x4 o;
  #pragma unroll
  for (int j = 0; j < 4; ++j) o[j] = d[j] * rs * gamma[tid * 4 + j] + beta[tid * 4 + j];
  *(f32x4*)(out + (size_t)row * HID + tid * 4) = o;
}

// ---------------- launch -----------------------------------------------------------------
extern "C" void kernel_launch(void* const* d_in, const int* in_sizes, int n_in,
                              void* d_out, int out_size, void* d_ws, size_t ws_size,
                              hipStream_t stream) {
  (void)in_sizes; (void)n_in; (void)out_size; (void)ws_size;
  const float* hid  = (const float*)d_in[0];
  const void*  mask = d_in[1];
  const float* rel  = (const float*)d_in[2];
  const float* wqk  = (const float*)d_in[3];
  const float* bqk  = (const float*)d_in[4];
  const float* wv   = (const float*)d_in[5];
  const float* bv   = (const float*)d_in[6];
  const float* wo   = (const float*)d_in[7];
  const float* bo   = (const float*)d_in[8];
  const float* ln_g = (const float*)d_in[9];
  const float* ln_b = (const float*)d_in[10];

  char* ws = (char*)d_ws;
  ushort* wcat     = (ushort*)(ws);                 //  6,291,456
  ushort* wo_b     = (ushort*)(ws + 6291456);       //  2,097,152
  float*  bcat     = (float*) (ws + 8388608);       //     12,288
  ushort* mask01   = (ushort*)(ws + 8400896);       //     16,384 (region 32,768)
  int*    idx_tab  = (int*)   (ws + 8433664);       //      4,096
  ushort* h_ext    = (ushort*)(ws + 8437760);       // 17,039,360  (reused as ctx)
  ushort* qkv      = (ushort*)(ws + 25477120);      // 51,118,080
  ushort* qp_b     = (ushort*)(ws + 76595200);      // 16,777,216 (bf16, scale inherited)
  ushort* pk_b     = (ushort*)(ws + 93372416);      // 16,777,216 (bf16, scale + mask)
  ushort* vt       = (ushort*)(ws + 110149632);     // 16,777,216
  char*   tmpr     = (ws + 126926848);              // 33,554,432 region
  ushort* ctx = h_ext;
  ushort* kc   = (ushort*)tmpr;                     // dead once k_attn finishes
  ushort* tmp0 = (ushort*)tmpr;                     // split-K partial 0 (16,777,216)
  ushort* tmp1 = (ushort*)(tmpr + 16777216);        // split-K partial 1 (16,777,216)

  k_conv_prep<<<4097, 256, 0, stream>>>(wqk, wv, wo, wcat, wo_b, mask, bqk, bv, mask01, idx_tab, bcat);
  k_ln1<<<MEXT, 256, 0, stream>>>(hid, rel, h_ext);
  k_gemm256<<<33 * (NQKV / 128), 512, 0, stream>>>(h_ext, wcat, bcat, qkv, MEXT, NQKV, 1024);
  k_vtpos<<<2304, 256, 0, stream>>>(qkv, mask01, vt, kc, qp_b, pk_b);
  k_attn<<<512, 512, 0, stream>>>(qkv, qp_b, pk_b, kc, vt, idx_tab, ctx);
  k_gemm_sk2<<<512, 512, 0, stream>>>(ctx, wo_b, bo, tmp0, tmp1);
  k_ln2<<<NROWS, 256, 0, stream>>>(tmp0, tmp1, ln_g, ln_b, (float*)d_out);
}

// Round 16
// 242.743 us; speedup vs baseline: 1.2391x; 1.0210x over previous
//
#include <hip/hip_runtime.h>
#include <hip/hip_bf16.h>

#define HID 1024
#define HEADS 16
#define HEAD 64
#define RELN 63
#define SEQ 512
#define BATCH 16
#define NROWS (SEQ*BATCH)      // 8192
#define MEXT 8320              // 8192 + 63, padded to 65*128
#define NQKV 3072
#define LNEPS 1e-7f
// 1/sqrt(3*64) * log2(e): folded into Q at the QKV-GEMM epilogue (base-2 domain)
#define SCALE2 (0.07216878364870323f * 1.4426950408889634f)

typedef __attribute__((ext_vector_type(4))) float  f32x4;
typedef __attribute__((ext_vector_type(8))) short  s16x8;
typedef __attribute__((ext_vector_type(4))) ushort u16x4;

static __device__ __forceinline__ ushort f2bf(float f) {
  __hip_bfloat16 h = __float2bfloat16(f);        // native RNE cvt
  return *reinterpret_cast<ushort*>(&h);
}
static __device__ __forceinline__ float bf2f(ushort u) {
  union { unsigned u; float f; } v; v.u = ((unsigned)u) << 16;
  return v.f;
}

// ---------------- fused pre-pass: weight convert (0..4095) | prep (4096) | LN1 (4097..) --
__global__ __launch_bounds__(256) void k_pre(const float* wqk, const float* wv, const float* wo,
                                             ushort* wcat, ushort* wo_b,
                                             const void* mask_raw, const float* bqk, const float* bv,
                                             ushort* mask01, int* idx_tab, float* bcat,
                                             const float* hid, const float* rel, ushort* h_ext) {
  int bid = blockIdx.x, tid = threadIdx.x;
  __shared__ float red[8];
  __shared__ int s_isbool;
  if (bid < 4096) {
    int c = bid * 256 + tid;    // 1,048,576 chunks of 4 elems
    f32x4 x; ushort* dst;
    if (c < 524288)      { x = *(const f32x4*)(wqk + (size_t)c * 4);            dst = wcat + (size_t)c * 4; }
    else if (c < 786432) { x = *(const f32x4*)(wv  + (size_t)(c - 524288) * 4); dst = wcat + (size_t)c * 4; }
    else                 { x = *(const f32x4*)(wo  + (size_t)(c - 786432) * 4); dst = wo_b + (size_t)(c - 786432) * 4; }
    u16x4 o = { f2bf(x[0]), f2bf(x[1]), f2bf(x[2]), f2bf(x[3]) };
    *(u16x4*)dst = o;
    return;
  }
  if (bid == 4096) {
    // ---- prep (one block) ----
    if (tid == 0) s_isbool = 0;
    __syncthreads();
    const unsigned* mu = (const unsigned*)mask_raw;
    int bad = 0;
    for (int i = tid; i < 2048; i += 256) if (mu[i] > 1u) bad = 1;
    if (bad) s_isbool = 1;              // benign race: any writer writes 1
    __syncthreads();
    int isbool = s_isbool;
    const unsigned char* m8 = (const unsigned char*)mask_raw;
    const int* m32 = (const int*)mask_raw;
    for (int i = tid; i < BATCH*SEQ; i += 256) {
      int m = isbool ? (int)m8[i] : m32[i];
      mask01[i] = m ? 1 : 0;
    }
    for (int i = tid; i < 1023; i += 256) {
      int r = i - 511;
      int a = r < 0 ? -r : r;
      int absp = (a < 16) ? 15 : (a < 511 ? a : 511);
      int idx;
      if (absp <= 16) idx = 31 + r;
      else {
        float v = logf((float)absp / 16.0f) / logf(511.0f / 16.0f) * 15.0f;
        int lp = (int)ceilf(v) + 16;
        idx = 31 + (r > 0 ? lp : -lp);
      }
      idx_tab[i] = idx;
    }
    for (int i = tid; i < 2048; i += 256) bcat[i] = bqk[i];
    for (int i = tid; i < 1024; i += 256) bcat[2048 + i] = bv[i];
    return;
  }
  // ---- LN1 (no affine) -> bf16, plus rel-embedding rows + zero pad ----
  int row = bid - 4097;
  if (row < NROWS) {
    const float* src = hid + (size_t)row * HID;
    f32x4 x = *(const f32x4*)(src + tid * 4);
    float s = x[0] + x[1] + x[2] + x[3];
    #pragma unroll
    for (int m = 1; m < 64; m <<= 1) s += __shfl_xor(s, m);
    if ((tid & 63) == 0) red[tid >> 6] = s;
    __syncthreads();
    float mean = (red[0] + red[1] + red[2] + red[3]) * (1.0f / HID);
    float d0 = x[0] - mean, d1 = x[1] - mean, d2 = x[2] - mean, d3 = x[3] - mean;
    float sq = d0*d0 + d1*d1 + d2*d2 + d3*d3;
    #pragma unroll
    for (int m = 1; m < 64; m <<= 1) sq += __shfl_xor(sq, m);
    __syncthreads();
    if ((tid & 63) == 0) red[4 + (tid >> 6)] = sq;
    __syncthreads();
    float var = (red[4] + red[5] + red[6] + red[7]) * (1.0f / HID);
    float rs = rsqrtf(var + LNEPS);
    u16x4 o = { f2bf(d0*rs), f2bf(d1*rs), f2bf(d2*rs), f2bf(d3*rs) };
    *(u16x4*)(h_ext + (size_t)row * HID + tid * 4) = o;
  } else if (row < NROWS + RELN) {
    const float* src = rel + (size_t)(row - NROWS) * HID;
    f32x4 x = *(const f32x4*)(src + tid * 4);
    u16x4 o = { f2bf(x[0]), f2bf(x[1]), f2bf(x[2]), f2bf(x[3]) };
    *(u16x4*)(h_ext + (size_t)row * HID + tid * 4) = o;
  } else {
    u16x4 z = { 0, 0, 0, 0 };
    *(u16x4*)(h_ext + (size_t)row * HID + tid * 4) = z;
  }
}

// ---------------- QKV GEMM: 256x128 tile, 8 waves, BK=64, swizzled global_load_lds -------
// Q columns (col<1024) pre-scaled by SCALE2 at the epilogue (base-2 attention domain).
__global__ __launch_bounds__(512) void k_gemm256(const ushort* A, const ushort* Bw, const float* bias,
                                                 ushort* Cb, int M, int N, int K) {
  __shared__ char smem[49152];
  char* As = smem;              // 256 x 64 bf16 = 32 KB
  char* Bs = smem + 32768;      // 128 x 64 bf16 = 16 KB
  int tid = threadIdx.x, lane = tid & 63, w = tid >> 6;
  int nbn = N >> 7;
  int per = gridDim.x >> 3;
  int gl = (blockIdx.x & 7) * per + (blockIdx.x >> 3);
  int bm = gl / nbn, bn = gl % nbn;
  int wr = w >> 1, wc = w & 1;           // 4x2 wave grid, 64x64 per wave
  int g = lane >> 4, r = lane & 15;
  f32x4 acc[4][4] = {};
  for (int ko = 0; ko < K; ko += 64) {
    __syncthreads();
    #pragma unroll
    for (int c = 0; c < 4; ++c) {        // A: 2048 chunks of 16B
      int chunk = c * 512 + tid;
      int row = chunk >> 3;
      int kbs = ((chunk & 7) << 4) ^ ((row & 7) << 4);
      int ar = bm * 256 + row; ar = ar < M ? ar : M - 1;
      const char* gA = (const char*)(A + (size_t)ar * K + ko) + kbs;
      __builtin_amdgcn_global_load_lds((const __attribute__((address_space(1))) void*)gA,
                                       (__attribute__((address_space(3))) void*)(As + c * 8192 + w * 1024),
                                       16, 0, 0);
    }
    #pragma unroll
    for (int c = 0; c < 2; ++c) {        // B: 1024 chunks of 16B
      int chunk = c * 512 + tid;
      int row = chunk >> 3;
      int kbs = ((chunk & 7) << 4) ^ ((row & 7) << 4);
      const char* gB = (const char*)(Bw + (size_t)(bn * 128 + row) * K + ko) + kbs;
      __builtin_amdgcn_global_load_lds((const __attribute__((address_space(1))) void*)gB,
                                       (__attribute__((address_space(3))) void*)(Bs + c * 8192 + w * 1024),
                                       16, 0, 0);
    }
    __syncthreads();
    #pragma unroll
    for (int kk = 0; kk < 2; ++kk) {
      s16x8 af[4], bf[4];
      #pragma unroll
      for (int mt = 0; mt < 4; ++mt) {
        int row = wr * 64 + mt * 16 + r;
        int kb = (kk * 64 + g * 16) ^ ((row & 7) << 4);
        af[mt] = *(const s16x8*)(As + row * 128 + kb);
      }
      #pragma unroll
      for (int nt = 0; nt < 4; ++nt) {
        int row = wc * 64 + nt * 16 + r;
        int kb = (kk * 64 + g * 16) ^ ((row & 7) << 4);
        bf[nt] = *(const s16x8*)(Bs + row * 128 + kb);
      }
      #pragma unroll
      for (int mt = 0; mt < 4; ++mt)
        #pragma unroll
        for (int nt = 0; nt < 4; ++nt)
          acc[mt][nt] = __builtin_amdgcn_mfma_f32_16x16x32_bf16(af[mt], bf[nt], acc[mt][nt], 0, 0, 0);
    }
  }
  #pragma unroll
  for (int nt = 0; nt < 4; ++nt) {
    int col = bn * 128 + wc * 64 + nt * 16 + r;
    float bvv = bias[col];
    float sc = (col < 1024) ? SCALE2 : 1.0f;   // fold attention scale into Q (and qpos)
    #pragma unroll
    for (int mt = 0; mt < 4; ++mt) {
      int row0 = bm * 256 + wr * 64 + mt * 16 + g * 4;
      #pragma unroll
      for (int i = 0; i < 4; ++i) {
        int row = row0 + i;
        if (row < M) Cb[(size_t)row * N + col] = f2bf((acc[mt][nt][i] + bvv) * sc);
      }
    }
  }
}

// ---------------- output GEMM: 256x128 tile, NO split-K, grid 256 = 1 block/CU -----------
__global__ __launch_bounds__(512) void k_gemm_out(const ushort* A, const ushort* Bw, const float* bias,
                                                  ushort* C) {
  const int N = 1024, K = 1024;
  __shared__ char smem[49152];
  char* As = smem;              // 256 x 64 bf16 = 32 KB
  char* Bs = smem + 32768;      // 128 x 64 bf16 = 16 KB
  int tid = threadIdx.x, lane = tid & 63, w = tid >> 6;
  int per = gridDim.x >> 3;
  int gl = (blockIdx.x & 7) * per + (blockIdx.x >> 3);
  int bm = gl >> 3, bn = gl & 7;         // bm-major per XCD chunk (A panel shared)
  int wr = w >> 1, wc = w & 1;
  int g = lane >> 4, r = lane & 15;
  f32x4 acc[4][4] = {};
  for (int ko = 0; ko < K; ko += 64) {
    __syncthreads();
    #pragma unroll
    for (int c = 0; c < 4; ++c) {        // A: 2048 chunks of 16B
      int chunk = c * 512 + tid;
      int row = chunk >> 3;
      int kbs = ((chunk & 7) << 4) ^ ((row & 7) << 4);
      const char* gA = (const char*)(A + (size_t)(bm * 256 + row) * K + ko) + kbs;
      __builtin_amdgcn_global_load_lds((const __attribute__((address_space(1))) void*)gA,
                                       (__attribute__((address_space(3))) void*)(As + c * 8192 + w * 1024),
                                       16, 0, 0);
    }
    #pragma unroll
    for (int c = 0; c < 2; ++c) {        // B: 1024 chunks of 16B
      int chunk = c * 512 + tid;
      int row = chunk >> 3;
      int kbs = ((chunk & 7) << 4) ^ ((row & 7) << 4);
      const char* gB = (const char*)(Bw + (size_t)(bn * 128 + row) * K + ko) + kbs;
      __builtin_amdgcn_global_load_lds((const __attribute__((address_space(1))) void*)gB,
                                       (__attribute__((address_space(3))) void*)(Bs + c * 8192 + w * 1024),
                                       16, 0, 0);
    }
    __syncthreads();
    #pragma unroll
    for (int kk = 0; kk < 2; ++kk) {
      s16x8 af[4], bf[4];
      #pragma unroll
      for (int mt = 0; mt < 4; ++mt) {
        int row = wr * 64 + mt * 16 + r;
        int kb = (kk * 64 + g * 16) ^ ((row & 7) << 4);
        af[mt] = *(const s16x8*)(As + row * 128 + kb);
      }
      #pragma unroll
      for (int nt = 0; nt < 4; ++nt) {
        int row = wc * 64 + nt * 16 + r;
        int kb = (kk * 64 + g * 16) ^ ((row & 7) << 4);
        bf[nt] = *(const s16x8*)(Bs + row * 128 + kb);
      }
      #pragma unroll
      for (int mt = 0; mt < 4; ++mt)
        #pragma unroll
        for (int nt = 0; nt < 4; ++nt)
          acc[mt][nt] = __builtin_amdgcn_mfma_f32_16x16x32_bf16(af[mt], bf[nt], acc[mt][nt], 0, 0, 0);
    }
  }
  #pragma unroll
  for (int nt = 0; nt < 4; ++nt) {
    int col = bn * 128 + wc * 64 + nt * 16 + r;
    float bvv = bias[col];
    #pragma unroll
    for (int mt = 0; mt < 4; ++mt) {
      int row0 = bm * 256 + wr * 64 + mt * 16 + g * 4;
      #pragma unroll
      for (int i = 0; i < 4; ++i)
        C[(size_t)(row0 + i) * N + col] = f2bf(acc[mt][nt][i] + bvv);
    }
  }
}

// ---------------- fused: V transpose + K repack (blocks <2048) | pos tables (>=2048) -----
__global__ __launch_bounds__(256) void k_vtpos(const ushort* qkv, const ushort* mask01,
                                               ushort* vt, ushort* kc, ushort* qp, ushort* pk) {
  int bid = blockIdx.x, tid = threadIdx.x;
  if (bid < 2048) {
    // ---- V transpose + K repack: vt[b,h,d,l], kc[b,h,l,d] ----
    int bh = bid >> 3, lt = bid & 7;
    int b = bh >> 4, h = bh & 15;
    __shared__ ushort tile[64][72];
    #pragma unroll
    for (int c = 0; c < 2; ++c) {
      int e = (c * 256 + tid) * 8;
      int l = e >> 6, d0 = e & 63;
      size_t row = (size_t)((lt * 64 + l) * 16 + b);
      s16x8 kv = *(const s16x8*)(qkv + row * NQKV + 1024 + h * 64 + d0);
      *(s16x8*)(kc + ((size_t)bh * SEQ + lt * 64 + l) * 64 + d0) = kv;   // contiguous K rows
      *(s16x8*)&tile[l][d0] = *(const s16x8*)(qkv + row * NQKV + 2048 + h * 64 + d0);
    }
    __syncthreads();
    #pragma unroll
    for (int c = 0; c < 2; ++c) {
      int e = (c * 256 + tid) * 8;
      int d = e >> 6, l0 = e & 63;
      ushort tmp[8];
      #pragma unroll
      for (int j = 0; j < 8; ++j) tmp[j] = tile[l0 + j][d];
      *(s16x8*)(vt + (size_t)(bh * 64 + d) * SEQ + lt * 64 + l0) = *(s16x8*)tmp;
    }
    return;
  }
  // ---- positional score tables (bf16, scale inherited from Q, mask baked into pk) ----
  int bh = bid - 2048;
  int b = bh >> 4, h = bh & 15;
  int lane = tid & 63, w = tid >> 6;
  int g = lane >> 4, r = lane & 15;
  __shared__ ushort mb[512];
  for (int i = tid; i < 512; i += 256) mb[i] = mask01[b * SEQ + i];
  __syncthreads();
  s16x8 bkp[4][2], bqp[4][2];   // kpos / qpos B-fragments (t = nt*16+r)
  #pragma unroll
  for (int nt = 0; nt < 4; ++nt)
    #pragma unroll
    for (int kk = 0; kk < 2; ++kk) {
      size_t rowp = (size_t)(NROWS + nt * 16 + r);
      int colq = h * 64 + kk * 32 + g * 8;
      bqp[nt][kk] = *(const s16x8*)(qkv + rowp * NQKV + colq);          // qpos (pre-scaled)
      bkp[nt][kk] = *(const s16x8*)(qkv + rowp * NQKV + 1024 + colq);   // kpos (unscaled)
    }
  for (int cc = 0; cc < 8; ++cc) {
    int rowbase = cc * 64 + w * 16;
    s16x8 aq[2], ak[2];
    #pragma unroll
    for (int kk = 0; kk < 2; ++kk) {
      size_t rowq = (size_t)((rowbase + r) * 16 + b);
      int colq = h * 64 + kk * 32 + g * 8;
      aq[kk] = *(const s16x8*)(qkv + rowq * NQKV + colq);               // q (pre-scaled)
      ak[kk] = *(const s16x8*)(qkv + rowq * NQKV + 1024 + colq);        // k (unscaled)
    }
    f32x4 accq[4] = {}, acck[4] = {};
    #pragma unroll
    for (int kk = 0; kk < 2; ++kk)
      #pragma unroll
      for (int nt = 0; nt < 4; ++nt) {
        accq[nt] = __builtin_amdgcn_mfma_f32_16x16x32_bf16(aq[kk], bkp[nt][kk], accq[nt], 0, 0, 0);
        acck[nt] = __builtin_amdgcn_mfma_f32_16x16x32_bf16(ak[kk], bqp[nt][kk], acck[nt], 0, 0, 0);
      }
    #pragma unroll
    for (int nt = 0; nt < 4; ++nt)
      #pragma unroll
      for (int i = 0; i < 4; ++i) {
        int q = rowbase + g * 4 + i;
        int t = nt * 16 + r;
        float biasv = mb[q] ? -1e9f : 0.0f;          // key-mask baked into pk rows
        qp[(size_t)bh * SEQ * 64 + q * 64 + t] = f2bf(accq[nt][i]);
        pk[(size_t)bh * SEQ * 64 + q * 64 + t] = f2bf(acck[nt][i] + biasv);
      }
  }
}

// ---------------- fused attention: BARRIER-FREE main loop (R11 structure, kt unroll 2) ---
__global__ __launch_bounds__(512) void k_attn(const ushort* qkv, const ushort* qp_all, const ushort* pk_all,
                                              const ushort* kc, const ushort* vt,
                                              const int* idx_tab, ushort* ctx) {
  int bid = blockIdx.x;
  int slot = bid >> 3;
  int bh = (bid & 7) * 32 + (slot >> 1);   // both q-halves of a bh on one XCD
  int qh = slot & 1;                       // which 256-row q half
  int b = bh >> 4, h = bh & 15;
  int tid = threadIdx.x, lane = tid & 63, w = tid >> 6;
  int g = lane >> 4, r = lane & 15;

  __shared__ ushort pk_f[512][68];   // 69,632 B  full-k pk table
  __shared__ ushort qp_s[256][68];   // 34,816 B  this half's qp rows
  __shared__ ushort p_s[8][16][68];  // 17,408 B  per-wave P staging (stride 68: conflict-free)
  __shared__ ushort idx_s[1024];     //  2,048 B  -> total 123,904 B

  const ushort* qpsrc = qp_all + (size_t)bh * SEQ * 64 + (size_t)qh * 256 * 64;
  const ushort* pksrc = pk_all + (size_t)bh * SEQ * 64;
  const char*   kcb   = (const char*)(kc + (size_t)bh * SEQ * 64);   // [l][d] 128B rows

  // ---- prologue: stage qp(256 rows), pk(512 rows), idx; load aq; ONE barrier ----
  #pragma unroll
  for (int c = 0; c < 4; ++c) {            // qp: 2048 chunks of 8 u16
    int chunk = c * 512 + tid;
    int row = chunk >> 3, col8 = (chunk & 7) * 8;
    s16x8 v = *(const s16x8*)(qpsrc + (size_t)row * 64 + col8);
    u16x4 lo = { (ushort)v[0], (ushort)v[1], (ushort)v[2], (ushort)v[3] };
    u16x4 hi = { (ushort)v[4], (ushort)v[5], (ushort)v[6], (ushort)v[7] };
    *(u16x4*)&qp_s[row][col8] = lo;
    *(u16x4*)&qp_s[row][col8 + 4] = hi;
  }
  #pragma unroll
  for (int c = 0; c < 8; ++c) {            // pk: 4096 chunks of 8 u16
    int chunk = c * 512 + tid;
    int row = chunk >> 3, col8 = (chunk & 7) * 8;
    s16x8 v = *(const s16x8*)(pksrc + (size_t)row * 64 + col8);
    u16x4 lo = { (ushort)v[0], (ushort)v[1], (ushort)v[2], (ushort)v[3] };
    u16x4 hi = { (ushort)v[4], (ushort)v[5], (ushort)v[6], (ushort)v[7] };
    *(u16x4*)&pk_f[row][col8] = lo;
    *(u16x4*)&pk_f[row][col8 + 4] = hi;
  }
  for (int i = tid; i < 1023; i += 512) idx_s[i] = (ushort)idx_tab[i];
  s16x8 aq[2][2];                          // [qs][kk] Q fragments (pre-scaled by SCALE2)
  #pragma unroll
  for (int qs = 0; qs < 2; ++qs)
    #pragma unroll
    for (int kk = 0; kk < 2; ++kk) {
      int qglob = qh * 256 + qs * 128 + w * 16 + r;
      aq[qs][kk] = *(const s16x8*)(qkv + ((size_t)qglob * 16 + b) * NQKV + h * 64 + kk * 32 + g * 8);
    }
  __syncthreads();   // the ONLY barrier

  float m_i[2] = { -3e38f, -3e38f }, l_i[2] = { 0.0f, 0.0f };
  f32x4 o_acc[2][4] = {};

  #pragma unroll 2
  for (int kt = 0; kt < 8; ++kt) {
    // K and V fragments straight from global (L2-shared across the block's 8 waves)
    s16x8 kf[4][2], vf[2][4];
    #pragma unroll
    for (int nt = 0; nt < 4; ++nt)
      #pragma unroll
      for (int kk = 0; kk < 2; ++kk)
        kf[nt][kk] = *(const s16x8*)(kcb + (size_t)(kt * 64 + nt * 16 + r) * 128 + kk * 64 + g * 16);
    #pragma unroll
    for (int kk = 0; kk < 2; ++kk)
      #pragma unroll
      for (int nt = 0; nt < 4; ++nt)
        vf[kk][nt] = *(const s16x8*)(vt + (size_t)(bh * 64 + nt * 16 + r) * SEQ + kt * 64 + kk * 32 + g * 8);

    #pragma unroll
    for (int qs = 0; qs < 2; ++qs) {
      // ---- swapped QK^T: lane holds S^T for q = r, k = nt*16+g*4+i ----
      f32x4 s[4];
      __builtin_amdgcn_s_setprio(1);
      #pragma unroll
      for (int nt = 0; nt < 4; ++nt) {
        f32x4 a = {};
        #pragma unroll
        for (int kk = 0; kk < 2; ++kk)
          a = __builtin_amdgcn_mfma_f32_16x16x32_bf16(kf[nt][kk], aq[qs][kk], a, 0, 0, 0);   // A=K, B=Q
        s[nt] = a;
      }
      __builtin_amdgcn_s_setprio(0);

      // ---- gather: v = c2c + qp_s[q][t] + pk_f[k][t]  (scale pre-folded, mask in pk) ----
      const ushort* qprow = &qp_s[qs * 128 + w * 16 + r][0];
      const int qg511 = qh * 256 + qs * 128 + w * 16 + r + 511;
      float m_loc = -3e38f;
      #pragma unroll
      for (int nt = 0; nt < 4; ++nt) {
        #pragma unroll
        for (int i = 0; i < 4; ++i) {
          int kg = kt * 64 + nt * 16 + g * 4 + i;
          int t = idx_s[qg511 - kg];
          float v = s[nt][i] + bf2f(qprow[t]) + bf2f(pk_f[kg][t]);
          s[nt][i] = v;
          m_loc = fmaxf(m_loc, v);
        }
      }

      // ---- row max across the 4 g-lanes holding q = r ----
      float mx = fmaxf(m_loc, __shfl_xor(m_loc, 16));
      mx = fmaxf(mx, __shfl_xor(mx, 32));

      // ---- T13 defer-rescale (base-2 threshold 8) ----
      if (__any(mx > m_i[qs] + 8.0f)) {
        float mnew = fmaxf(m_i[qs], mx);
        float rs = exp2f(m_i[qs] - mnew);
        m_i[qs] = mnew;
        l_i[qs] *= rs;
        float rsb[4];
        #pragma unroll
        for (int i = 0; i < 4; ++i) rsb[i] = __shfl(rs, g * 4 + i);   // rs for q = g*4+i
        #pragma unroll
        for (int nt = 0; nt < 4; ++nt)
          #pragma unroll
          for (int i = 0; i < 4; ++i) o_acc[qs][nt][i] *= rsb[i];
      }

      // ---- exp2 + P pack (b64 LDS writes), psum ----
      float psum = 0.0f;
      #pragma unroll
      for (int nt = 0; nt < 4; ++nt) {
        u16x4 pk4;
        #pragma unroll
        for (int i = 0; i < 4; ++i) {
          float pe = exp2f(s[nt][i] - m_i[qs]);   // masked: huge negative -> exact 0
          psum += pe;
          pk4[i] = f2bf(pe);
        }
        *(u16x4*)&p_s[w][r][nt * 16 + g * 4] = pk4;
      }
      psum += __shfl_xor(psum, 16);
      psum += __shfl_xor(psum, 32);
      l_i[qs] += psum;

      // ---- PV (2 x b64 p reads; per-wave roundtrip ordered by lgkmcnt) ----
      __builtin_amdgcn_s_setprio(1);
      #pragma unroll
      for (int kk = 0; kk < 2; ++kk) {
        u16x4 lo = *(const u16x4*)&p_s[w][r][kk * 32 + g * 8];
        u16x4 hi = *(const u16x4*)&p_s[w][r][kk * 32 + g * 8 + 4];
        s16x8 pa = { (short)lo[0], (short)lo[1], (short)lo[2], (short)lo[3],
                     (short)hi[0], (short)hi[1], (short)hi[2], (short)hi[3] };
        #pragma unroll
        for (int nt = 0; nt < 4; ++nt)
          o_acc[qs][nt] = __builtin_amdgcn_mfma_f32_16x16x32_bf16(pa, vf[kk][nt], o_acc[qs][nt], 0, 0, 0);
      }
      __builtin_amdgcn_s_setprio(0);
    }
  }

  #pragma unroll
  for (int qs = 0; qs < 2; ++qs) {
    float lb[4];
    #pragma unroll
    for (int i = 0; i < 4; ++i) lb[i] = __shfl(l_i[qs], g * 4 + i);   // l for q = g*4+i
    #pragma unroll
    for (int i = 0; i < 4; ++i) {
      float inv = lb[i] > 0.0f ? 1.0f / lb[i] : 0.0f;
      int lq = qh * 256 + qs * 128 + w * 16 + g * 4 + i;
      size_t rowc = (size_t)(lq * 16 + b);
      #pragma unroll
      for (int nt = 0; nt < 4; ++nt)
        ctx[rowc * HID + h * 64 + nt * 16 + r] = f2bf(o_acc[qs][nt][i] * inv);
    }
  }
}

// ---------------- LN2 (affine), bf16 in -> f32 out ---------------------------------------
__global__ __launch_bounds__(256) void k_ln2(const ushort* t0,
                                             const float* gamma, const float* beta, float* out) {
  int row = blockIdx.x, tid = threadIdx.x;
  __shared__ float red[8];
  u16x4 xa = *(const u16x4*)(t0 + (size_t)row * HID + tid * 4);
  float x[4] = { bf2f(xa[0]), bf2f(xa[1]), bf2f(xa[2]), bf2f(xa[3]) };
  float s = x[0] + x[1] + x[2] + x[3];
  #pragma unroll
  for (int m = 1; m < 64; m <<= 1) s += __shfl_xor(s, m);
  if ((tid & 63) == 0) red[tid >> 6] = s;
  __syncthreads();
  float mean = (red[0] + red[1] + red[2] + red[3]) * (1.0f / HID);
  float d[4]; float sq = 0.0f;
  #pragma unroll
  for (int j = 0; j < 4; ++j) { d[j] = x[j] - mean; sq += d[j] * d[j]; }
  #pragma unroll
  for (int m = 1; m < 64; m <<= 1) sq += __shfl_xor(sq, m);
  __syncthreads();
  if ((tid & 63) == 0) red[4 + (tid >> 6)] = sq;
  __syncthreads();
  float var = (red[4] + red[5] + red[6] + red[7]) * (1.0f / HID);
  float rs = rsqrtf(var + LNEPS);
  f32x4 o;
  #pragma unroll
  for (int j = 0; j < 4; ++j) o[j] = d[j] * rs * gamma[tid * 4 + j] + beta[tid * 4 + j];
  *(f32x4*)(out + (size_t)row * HID + tid * 4) = o;
}

// ---------------- launch -----------------------------------------------------------------
extern "C" void kernel_launch(void* const* d_in, const int* in_sizes, int n_in,
                              void* d_out, int out_size, void* d_ws, size_t ws_size,
                              hipStream_t stream) {
  (void)in_sizes; (void)n_in; (void)out_size; (void)ws_size;
  const float* hid  = (const float*)d_in[0];
  const void*  mask = d_in[1];
  const float* rel  = (const float*)d_in[2];
  const float* wqk  = (const float*)d_in[3];
  const float* bqk  = (const float*)d_in[4];
  const float* wv   = (const float*)d_in[5];
  const float* bv   = (const float*)d_in[6];
  const float* wo   = (const float*)d_in[7];
  const float* bo   = (const float*)d_in[8];
  const float* ln_g = (const float*)d_in[9];
  const float* ln_b = (const float*)d_in[10];

  char* ws = (char*)d_ws;
  ushort* wcat     = (ushort*)(ws);                 //  6,291,456
  ushort* wo_b     = (ushort*)(ws + 6291456);       //  2,097,152
  float*  bcat     = (float*) (ws + 8388608);       //     12,288
  ushort* mask01   = (ushort*)(ws + 8400896);       //     16,384 (region 32,768)
  int*    idx_tab  = (int*)   (ws + 8433664);       //      4,096
  ushort* h_ext    = (ushort*)(ws + 8437760);       // 17,039,360  (reused as ctx)
  ushort* qkv      = (ushort*)(ws + 25477120);      // 51,118,080
  ushort* qp_b     = (ushort*)(ws + 76595200);      // 16,777,216 (bf16, scale inherited)
  ushort* pk_b     = (ushort*)(ws + 93372416);      // 16,777,216 (bf16, scale + mask)
  ushort* vt       = (ushort*)(ws + 110149632);     // 16,777,216
  char*   tmpr     = (ws + 126926848);              // 33,554,432 region
  ushort* ctx = h_ext;
  ushort* kc   = (ushort*)tmpr;                     // dead once k_attn finishes
  ushort* tmp0 = (ushort*)tmpr;                     // output-GEMM bf16 result (16,777,216)

  k_pre<<<4097 + MEXT, 256, 0, stream>>>(wqk, wv, wo, wcat, wo_b, mask, bqk, bv,
                                         mask01, idx_tab, bcat, hid, rel, h_ext);
  k_gemm256<<<33 * (NQKV / 128), 512, 0, stream>>>(h_ext, wcat, bcat, qkv, MEXT, NQKV, 1024);
  k_vtpos<<<2304, 256, 0, stream>>>(qkv, mask01, vt, kc, qp_b, pk_b);
  k_attn<<<512, 512, 0, stream>>>(qkv, qp_b, pk_b, kc, vt, idx_tab, ctx);
  k_gemm_out<<<256, 512, 0, stream>>>(ctx, wo_b, bo, tmp0);
  k_ln2<<<NROWS, 256, 0, stream>>>(tmp0, ln_g, ln_b, (float*)d_out);
}

// Round 17
// 239.593 us; speedup vs baseline: 1.2554x; 1.0131x over previous
//
#include <hip/hip_runtime.h>
#include <hip/hip_bf16.h>

#define HID 1024
#define HEADS 16
#define HEAD 64
#define RELN 63
#define SEQ 512
#define BATCH 16
#define NROWS (SEQ*BATCH)      // 8192
#define MEXT 8320              // 8192 + 63, padded to 65*128
#define NQKV 3072
#define LNEPS 1e-7f
// 1/sqrt(3*64) * log2(e): folded into Q at the QKV-GEMM epilogue (base-2 domain)
#define SCALE2 (0.07216878364870323f * 1.4426950408889634f)

typedef __attribute__((ext_vector_type(4))) float  f32x4;
typedef __attribute__((ext_vector_type(8))) short  s16x8;
typedef __attribute__((ext_vector_type(4))) ushort u16x4;

static __device__ __forceinline__ ushort f2bf(float f) {
  __hip_bfloat16 h = __float2bfloat16(f);        // native RNE cvt
  return *reinterpret_cast<ushort*>(&h);
}
static __device__ __forceinline__ float bf2f(ushort u) {
  union { unsigned u; float f; } v; v.u = ((unsigned)u) << 16;
  return v.f;
}

// ---------------- fused pre-pass: weight convert (0..4095) | prep (4096) | LN1 (4097..) --
__global__ __launch_bounds__(256) void k_pre(const float* wqk, const float* wv, const float* wo,
                                             ushort* wcat, ushort* wo_b,
                                             const void* mask_raw, const float* bqk, const float* bv,
                                             ushort* mask01, int* idx_tab, float* bcat,
                                             const float* hid, const float* rel, ushort* h_ext) {
  int bid = blockIdx.x, tid = threadIdx.x;
  __shared__ float red[8];
  __shared__ int s_isbool;
  if (bid < 4096) {
    int c = bid * 256 + tid;    // 1,048,576 chunks of 4 elems
    f32x4 x; ushort* dst;
    if (c < 524288)      { x = *(const f32x4*)(wqk + (size_t)c * 4);            dst = wcat + (size_t)c * 4; }
    else if (c < 786432) { x = *(const f32x4*)(wv  + (size_t)(c - 524288) * 4); dst = wcat + (size_t)c * 4; }
    else                 { x = *(const f32x4*)(wo  + (size_t)(c - 786432) * 4); dst = wo_b + (size_t)(c - 786432) * 4; }
    u16x4 o = { f2bf(x[0]), f2bf(x[1]), f2bf(x[2]), f2bf(x[3]) };
    *(u16x4*)dst = o;
    return;
  }
  if (bid == 4096) {
    // ---- prep (one block) ----
    if (tid == 0) s_isbool = 0;
    __syncthreads();
    const unsigned* mu = (const unsigned*)mask_raw;
    int bad = 0;
    for (int i = tid; i < 2048; i += 256) if (mu[i] > 1u) bad = 1;
    if (bad) s_isbool = 1;              // benign race: any writer writes 1
    __syncthreads();
    int isbool = s_isbool;
    const unsigned char* m8 = (const unsigned char*)mask_raw;
    const int* m32 = (const int*)mask_raw;
    for (int i = tid; i < BATCH*SEQ; i += 256) {
      int m = isbool ? (int)m8[i] : m32[i];
      mask01[i] = m ? 1 : 0;
    }
    for (int i = tid; i < 1023; i += 256) {
      int r = i - 511;
      int a = r < 0 ? -r : r;
      int absp = (a < 16) ? 15 : (a < 511 ? a : 511);
      int idx;
      if (absp <= 16) idx = 31 + r;
      else {
        float v = logf((float)absp / 16.0f) / logf(511.0f / 16.0f) * 15.0f;
        int lp = (int)ceilf(v) + 16;
        idx = 31 + (r > 0 ? lp : -lp);
      }
      idx_tab[i] = idx;
    }
    for (int i = tid; i < 2048; i += 256) bcat[i] = bqk[i];
    for (int i = tid; i < 1024; i += 256) bcat[2048 + i] = bv[i];
    return;
  }
  // ---- LN1 (no affine) -> bf16, plus rel-embedding rows + zero pad ----
  int row = bid - 4097;
  if (row < NROWS) {
    const float* src = hid + (size_t)row * HID;
    f32x4 x = *(const f32x4*)(src + tid * 4);
    float s = x[0] + x[1] + x[2] + x[3];
    #pragma unroll
    for (int m = 1; m < 64; m <<= 1) s += __shfl_xor(s, m);
    if ((tid & 63) == 0) red[tid >> 6] = s;
    __syncthreads();
    float mean = (red[0] + red[1] + red[2] + red[3]) * (1.0f / HID);
    float d0 = x[0] - mean, d1 = x[1] - mean, d2 = x[2] - mean, d3 = x[3] - mean;
    float sq = d0*d0 + d1*d1 + d2*d2 + d3*d3;
    #pragma unroll
    for (int m = 1; m < 64; m <<= 1) sq += __shfl_xor(sq, m);
    __syncthreads();
    if ((tid & 63) == 0) red[4 + (tid >> 6)] = sq;
    __syncthreads();
    float var = (red[4] + red[5] + red[6] + red[7]) * (1.0f / HID);
    float rs = rsqrtf(var + LNEPS);
    u16x4 o = { f2bf(d0*rs), f2bf(d1*rs), f2bf(d2*rs), f2bf(d3*rs) };
    *(u16x4*)(h_ext + (size_t)row * HID + tid * 4) = o;
  } else if (row < NROWS + RELN) {
    const float* src = rel + (size_t)(row - NROWS) * HID;
    f32x4 x = *(const f32x4*)(src + tid * 4);
    u16x4 o = { f2bf(x[0]), f2bf(x[1]), f2bf(x[2]), f2bf(x[3]) };
    *(u16x4*)(h_ext + (size_t)row * HID + tid * 4) = o;
  } else {
    u16x4 z = { 0, 0, 0, 0 };
    *(u16x4*)(h_ext + (size_t)row * HID + tid * 4) = z;
  }
}

// ---------------- QKV GEMM: 256x128 tile, 8 waves, BK=64, swizzled global_load_lds -------
// Q columns (col<1024) pre-scaled by SCALE2 at the epilogue (base-2 attention domain).
__global__ __launch_bounds__(512) void k_gemm256(const ushort* A, const ushort* Bw, const float* bias,
                                                 ushort* Cb, int M, int N, int K) {
  __shared__ char smem[49152];
  char* As = smem;              // 256 x 64 bf16 = 32 KB
  char* Bs = smem + 32768;      // 128 x 64 bf16 = 16 KB
  int tid = threadIdx.x, lane = tid & 63, w = tid >> 6;
  int nbn = N >> 7;
  int per = gridDim.x >> 3;
  int gl = (blockIdx.x & 7) * per + (blockIdx.x >> 3);
  int bm = gl / nbn, bn = gl % nbn;
  int wr = w >> 1, wc = w & 1;           // 4x2 wave grid, 64x64 per wave
  int g = lane >> 4, r = lane & 15;
  f32x4 acc[4][4] = {};
  for (int ko = 0; ko < K; ko += 64) {
    __syncthreads();
    #pragma unroll
    for (int c = 0; c < 4; ++c) {        // A: 2048 chunks of 16B
      int chunk = c * 512 + tid;
      int row = chunk >> 3;
      int kbs = ((chunk & 7) << 4) ^ ((row & 7) << 4);
      int ar = bm * 256 + row; ar = ar < M ? ar : M - 1;
      const char* gA = (const char*)(A + (size_t)ar * K + ko) + kbs;
      __builtin_amdgcn_global_load_lds((const __attribute__((address_space(1))) void*)gA,
                                       (__attribute__((address_space(3))) void*)(As + c * 8192 + w * 1024),
                                       16, 0, 0);
    }
    #pragma unroll
    for (int c = 0; c < 2; ++c) {        // B: 1024 chunks of 16B
      int chunk = c * 512 + tid;
      int row = chunk >> 3;
      int kbs = ((chunk & 7) << 4) ^ ((row & 7) << 4);
      const char* gB = (const char*)(Bw + (size_t)(bn * 128 + row) * K + ko) + kbs;
      __builtin_amdgcn_global_load_lds((const __attribute__((address_space(1))) void*)gB,
                                       (__attribute__((address_space(3))) void*)(Bs + c * 8192 + w * 1024),
                                       16, 0, 0);
    }
    __syncthreads();
    #pragma unroll
    for (int kk = 0; kk < 2; ++kk) {
      s16x8 af[4], bf[4];
      #pragma unroll
      for (int mt = 0; mt < 4; ++mt) {
        int row = wr * 64 + mt * 16 + r;
        int kb = (kk * 64 + g * 16) ^ ((row & 7) << 4);
        af[mt] = *(const s16x8*)(As + row * 128 + kb);
      }
      #pragma unroll
      for (int nt = 0; nt < 4; ++nt) {
        int row = wc * 64 + nt * 16 + r;
        int kb = (kk * 64 + g * 16) ^ ((row & 7) << 4);
        bf[nt] = *(const s16x8*)(Bs + row * 128 + kb);
      }
      #pragma unroll
      for (int mt = 0; mt < 4; ++mt)
        #pragma unroll
        for (int nt = 0; nt < 4; ++nt)
          acc[mt][nt] = __builtin_amdgcn_mfma_f32_16x16x32_bf16(af[mt], bf[nt], acc[mt][nt], 0, 0, 0);
    }
  }
  #pragma unroll
  for (int nt = 0; nt < 4; ++nt) {
    int col = bn * 128 + wc * 64 + nt * 16 + r;
    float bvv = bias[col];
    float sc = (col < 1024) ? SCALE2 : 1.0f;   // fold attention scale into Q (and qpos)
    #pragma unroll
    for (int mt = 0; mt < 4; ++mt) {
      int row0 = bm * 256 + wr * 64 + mt * 16 + g * 4;
      #pragma unroll
      for (int i = 0; i < 4; ++i) {
        int row = row0 + i;
        if (row < M) Cb[(size_t)row * N + col] = f2bf((acc[mt][nt][i] + bvv) * sc);
      }
    }
  }
}

// ---------------- output GEMM: 256x128 tile, NO split-K, grid 256 = 1 block/CU -----------
__global__ __launch_bounds__(512) void k_gemm_out(const ushort* A, const ushort* Bw, const float* bias,
                                                  ushort* C) {
  const int N = 1024, K = 1024;
  __shared__ char smem[49152];
  char* As = smem;              // 256 x 64 bf16 = 32 KB
  char* Bs = smem + 32768;      // 128 x 64 bf16 = 16 KB
  int tid = threadIdx.x, lane = tid & 63, w = tid >> 6;
  int per = gridDim.x >> 3;
  int gl = (blockIdx.x & 7) * per + (blockIdx.x >> 3);
  int bm = gl >> 3, bn = gl & 7;         // bm-major per XCD chunk (A panel shared)
  int wr = w >> 1, wc = w & 1;
  int g = lane >> 4, r = lane & 15;
  f32x4 acc[4][4] = {};
  for (int ko = 0; ko < K; ko += 64) {
    __syncthreads();
    #pragma unroll
    for (int c = 0; c < 4; ++c) {        // A: 2048 chunks of 16B
      int chunk = c * 512 + tid;
      int row = chunk >> 3;
      int kbs = ((chunk & 7) << 4) ^ ((row & 7) << 4);
      const char* gA = (const char*)(A + (size_t)(bm * 256 + row) * K + ko) + kbs;
      __builtin_amdgcn_global_load_lds((const __attribute__((address_space(1))) void*)gA,
                                       (__attribute__((address_space(3))) void*)(As + c * 8192 + w * 1024),
                                       16, 0, 0);
    }
    #pragma unroll
    for (int c = 0; c < 2; ++c) {        // B: 1024 chunks of 16B
      int chunk = c * 512 + tid;
      int row = chunk >> 3;
      int kbs = ((chunk & 7) << 4) ^ ((row & 7) << 4);
      const char* gB = (const char*)(Bw + (size_t)(bn * 128 + row) * K + ko) + kbs;
      __builtin_amdgcn_global_load_lds((const __attribute__((address_space(1))) void*)gB,
                                       (__attribute__((address_space(3))) void*)(Bs + c * 8192 + w * 1024),
                                       16, 0, 0);
    }
    __syncthreads();
    #pragma unroll
    for (int kk = 0; kk < 2; ++kk) {
      s16x8 af[4], bf[4];
      #pragma unroll
      for (int mt = 0; mt < 4; ++mt) {
        int row = wr * 64 + mt * 16 + r;
        int kb = (kk * 64 + g * 16) ^ ((row & 7) << 4);
        af[mt] = *(const s16x8*)(As + row * 128 + kb);
      }
      #pragma unroll
      for (int nt = 0; nt < 4; ++nt) {
        int row = wc * 64 + nt * 16 + r;
        int kb = (kk * 64 + g * 16) ^ ((row & 7) << 4);
        bf[nt] = *(const s16x8*)(Bs + row * 128 + kb);
      }
      #pragma unroll
      for (int mt = 0; mt < 4; ++mt)
        #pragma unroll
        for (int nt = 0; nt < 4; ++nt)
          acc[mt][nt] = __builtin_amdgcn_mfma_f32_16x16x32_bf16(af[mt], bf[nt], acc[mt][nt], 0, 0, 0);
    }
  }
  #pragma unroll
  for (int nt = 0; nt < 4; ++nt) {
    int col = bn * 128 + wc * 64 + nt * 16 + r;
    float bvv = bias[col];
    #pragma unroll
    for (int mt = 0; mt < 4; ++mt) {
      int row0 = bm * 256 + wr * 64 + mt * 16 + g * 4;
      #pragma unroll
      for (int i = 0; i < 4; ++i)
        C[(size_t)(row0 + i) * N + col] = f2bf(acc[mt][nt][i] + bvv);
    }
  }
}

// ---------------- fused: V transpose + K repack (blocks <2048) | pos tables (>=2048) -----
__global__ __launch_bounds__(256) void k_vtpos(const ushort* qkv, const ushort* mask01,
                                               ushort* vt, ushort* kc, ushort* qp, ushort* pk) {
  int bid = blockIdx.x, tid = threadIdx.x;
  if (bid < 2048) {
    // ---- V transpose + K repack: vt[b,h,d,l], kc[b,h,l,d] ----
    int bh = bid >> 3, lt = bid & 7;
    int b = bh >> 4, h = bh & 15;
    __shared__ ushort tile[64][72];
    #pragma unroll
    for (int c = 0; c < 2; ++c) {
      int e = (c * 256 + tid) * 8;
      int l = e >> 6, d0 = e & 63;
      size_t row = (size_t)((lt * 64 + l) * 16 + b);
      s16x8 kv = *(const s16x8*)(qkv + row * NQKV + 1024 + h * 64 + d0);
      *(s16x8*)(kc + ((size_t)bh * SEQ + lt * 64 + l) * 64 + d0) = kv;   // contiguous K rows
      *(s16x8*)&tile[l][d0] = *(const s16x8*)(qkv + row * NQKV + 2048 + h * 64 + d0);
    }
    __syncthreads();
    #pragma unroll
    for (int c = 0; c < 2; ++c) {
      int e = (c * 256 + tid) * 8;
      int d = e >> 6, l0 = e & 63;
      ushort tmp[8];
      #pragma unroll
      for (int j = 0; j < 8; ++j) tmp[j] = tile[l0 + j][d];
      *(s16x8*)(vt + (size_t)(bh * 64 + d) * SEQ + lt * 64 + l0) = *(s16x8*)tmp;
    }
    return;
  }
  // ---- positional score tables (bf16, scale inherited from Q, mask baked into pk) ----
  int bh = bid - 2048;
  int b = bh >> 4, h = bh & 15;
  int lane = tid & 63, w = tid >> 6;
  int g = lane >> 4, r = lane & 15;
  __shared__ ushort mb[512];
  for (int i = tid; i < 512; i += 256) mb[i] = mask01[b * SEQ + i];
  __syncthreads();
  s16x8 bkp[4][2], bqp[4][2];   // kpos / qpos B-fragments (t = nt*16+r)
  #pragma unroll
  for (int nt = 0; nt < 4; ++nt)
    #pragma unroll
    for (int kk = 0; kk < 2; ++kk) {
      size_t rowp = (size_t)(NROWS + nt * 16 + r);
      int colq = h * 64 + kk * 32 + g * 8;
      bqp[nt][kk] = *(const s16x8*)(qkv + rowp * NQKV + colq);          // qpos (pre-scaled)
      bkp[nt][kk] = *(const s16x8*)(qkv + rowp * NQKV + 1024 + colq);   // kpos (unscaled)
    }
  for (int cc = 0; cc < 8; ++cc) {
    int rowbase = cc * 64 + w * 16;
    s16x8 aq[2], ak[2];
    #pragma unroll
    for (int kk = 0; kk < 2; ++kk) {
      size_t rowq = (size_t)((rowbase + r) * 16 + b);
      int colq = h * 64 + kk * 32 + g * 8;
      aq[kk] = *(const s16x8*)(qkv + rowq * NQKV + colq);               // q (pre-scaled)
      ak[kk] = *(const s16x8*)(qkv + rowq * NQKV + 1024 + colq);        // k (unscaled)
    }
    f32x4 accq[4] = {}, acck[4] = {};
    #pragma unroll
    for (int kk = 0; kk < 2; ++kk)
      #pragma unroll
      for (int nt = 0; nt < 4; ++nt) {
        accq[nt] = __builtin_amdgcn_mfma_f32_16x16x32_bf16(aq[kk], bkp[nt][kk], accq[nt], 0, 0, 0);
        acck[nt] = __builtin_amdgcn_mfma_f32_16x16x32_bf16(ak[kk], bqp[nt][kk], acck[nt], 0, 0, 0);
      }
    #pragma unroll
    for (int nt = 0; nt < 4; ++nt)
      #pragma unroll
      for (int i = 0; i < 4; ++i) {
        int q = rowbase + g * 4 + i;
        int t = nt * 16 + r;
        float biasv = mb[q] ? -1e9f : 0.0f;          // key-mask baked into pk rows
        qp[(size_t)bh * SEQ * 64 + q * 64 + t] = f2bf(accq[nt][i]);
        pk[(size_t)bh * SEQ * 64 + q * 64 + t] = f2bf(acck[nt][i] + biasv);
      }
  }
}

// ---------------- fused attention: whole-bh blocks (grid 256), barrier-free --------------
// One block per (b,h): BOTH tables staged once (158.7 KB LDS); each wave owns FOUR
// 16-row q-subtiles, so per-kt K/V loads amortize over 4x the compute. 1 block/CU.
__global__ __launch_bounds__(512) void k_attn(const ushort* qkv, const ushort* qp_all, const ushort* pk_all,
                                              const ushort* kc, const ushort* vt,
                                              const int* idx_tab, ushort* ctx) {
  int bid = blockIdx.x;
  int bh = (bid & 7) * 32 + (bid >> 3);    // XCD-chunked over the 256 (b,h) pairs
  int b = bh >> 4, h = bh & 15;
  int tid = threadIdx.x, lane = tid & 63, w = tid >> 6;
  int g = lane >> 4, r = lane & 15;

  __shared__ ushort pk_f[512][68];   // 69,632 B  full-k pk table
  __shared__ ushort qp_f[512][68];   // 69,632 B  full-q qp table
  __shared__ ushort p_s[8][16][68];  // 17,408 B  per-wave P staging (stride 68: conflict-free)
  __shared__ ushort idx_s[1024];     //  2,048 B  -> total 158,720 B (<= 160 KiB)

  const ushort* qpsrc = qp_all + (size_t)bh * SEQ * 64;
  const ushort* pksrc = pk_all + (size_t)bh * SEQ * 64;
  const char*   kcb   = (const char*)(kc + (size_t)bh * SEQ * 64);   // [l][d] 128B rows

  // ---- prologue: stage qp(512), pk(512), idx; load aq; ONE barrier ----
  #pragma unroll
  for (int c = 0; c < 8; ++c) {            // 4096 chunks of 8 u16 each table
    int chunk = c * 512 + tid;
    int row = chunk >> 3, col8 = (chunk & 7) * 8;
    s16x8 vq = *(const s16x8*)(qpsrc + (size_t)row * 64 + col8);
    s16x8 vp = *(const s16x8*)(pksrc + (size_t)row * 64 + col8);
    u16x4 qlo = { (ushort)vq[0], (ushort)vq[1], (ushort)vq[2], (ushort)vq[3] };
    u16x4 qhi = { (ushort)vq[4], (ushort)vq[5], (ushort)vq[6], (ushort)vq[7] };
    u16x4 plo = { (ushort)vp[0], (ushort)vp[1], (ushort)vp[2], (ushort)vp[3] };
    u16x4 phi = { (ushort)vp[4], (ushort)vp[5], (ushort)vp[6], (ushort)vp[7] };
    *(u16x4*)&qp_f[row][col8] = qlo;
    *(u16x4*)&qp_f[row][col8 + 4] = qhi;
    *(u16x4*)&pk_f[row][col8] = plo;
    *(u16x4*)&pk_f[row][col8 + 4] = phi;
  }
  for (int i = tid; i < 1023; i += 512) idx_s[i] = (ushort)idx_tab[i];
  s16x8 aq[4][2];                          // [qs][kk] Q fragments (pre-scaled by SCALE2)
  #pragma unroll
  for (int qs = 0; qs < 4; ++qs)
    #pragma unroll
    for (int kk = 0; kk < 2; ++kk) {
      int qglob = qs * 128 + w * 16 + r;
      aq[qs][kk] = *(const s16x8*)(qkv + ((size_t)qglob * 16 + b) * NQKV + h * 64 + kk * 32 + g * 8);
    }
  __syncthreads();   // the ONLY barrier

  float m_i[4] = { -3e38f, -3e38f, -3e38f, -3e38f }, l_i[4] = { 0.0f, 0.0f, 0.0f, 0.0f };
  f32x4 o_acc[4][4] = {};

  for (int kt = 0; kt < 8; ++kt) {
    // K and V fragments straight from global (L2-shared across the block's 8 waves)
    s16x8 kf[4][2], vf[2][4];
    #pragma unroll
    for (int nt = 0; nt < 4; ++nt)
      #pragma unroll
      for (int kk = 0; kk < 2; ++kk)
        kf[nt][kk] = *(const s16x8*)(kcb + (size_t)(kt * 64 + nt * 16 + r) * 128 + kk * 64 + g * 16);
    #pragma unroll
    for (int kk = 0; kk < 2; ++kk)
      #pragma unroll
      for (int nt = 0; nt < 4; ++nt)
        vf[kk][nt] = *(const s16x8*)(vt + (size_t)(bh * 64 + nt * 16 + r) * SEQ + kt * 64 + kk * 32 + g * 8);

    #pragma unroll
    for (int qs = 0; qs < 4; ++qs) {
      // ---- swapped QK^T: lane holds S^T for q = r, k = nt*16+g*4+i ----
      f32x4 s[4];
      __builtin_amdgcn_s_setprio(1);
      #pragma unroll
      for (int nt = 0; nt < 4; ++nt) {
        f32x4 a = {};
        #pragma unroll
        for (int kk = 0; kk < 2; ++kk)
          a = __builtin_amdgcn_mfma_f32_16x16x32_bf16(kf[nt][kk], aq[qs][kk], a, 0, 0, 0);   // A=K, B=Q
        s[nt] = a;
      }
      __builtin_amdgcn_s_setprio(0);

      // ---- gather: v = c2c + qp_f[q][t] + pk_f[k][t]  (scale pre-folded, mask in pk) ----
      const ushort* qprow = &qp_f[qs * 128 + w * 16 + r][0];
      const int qg511 = qs * 128 + w * 16 + r + 511;
      float m_loc = -3e38f;
      #pragma unroll
      for (int nt = 0; nt < 4; ++nt) {
        #pragma unroll
        for (int i = 0; i < 4; ++i) {
          int kg = kt * 64 + nt * 16 + g * 4 + i;
          int t = idx_s[qg511 - kg];
          float v = s[nt][i] + bf2f(qprow[t]) + bf2f(pk_f[kg][t]);
          s[nt][i] = v;
          m_loc = fmaxf(m_loc, v);
        }
      }

      // ---- row max across the 4 g-lanes holding q = r ----
      float mx = fmaxf(m_loc, __shfl_xor(m_loc, 16));
      mx = fmaxf(mx, __shfl_xor(mx, 32));

      // ---- T13 defer-rescale (base-2 threshold 8) ----
      if (__any(mx > m_i[qs] + 8.0f)) {
        float mnew = fmaxf(m_i[qs], mx);
        float rs = exp2f(m_i[qs] - mnew);
        m_i[qs] = mnew;
        l_i[qs] *= rs;
        float rsb[4];
        #pragma unroll
        for (int i = 0; i < 4; ++i) rsb[i] = __shfl(rs, g * 4 + i);   // rs for q = g*4+i
        #pragma unroll
        for (int nt = 0; nt < 4; ++nt)
          #pragma unroll
          for (int i = 0; i < 4; ++i) o_acc[qs][nt][i] *= rsb[i];
      }

      // ---- exp2 + P pack (b64 LDS writes), psum ----
      float psum = 0.0f;
      #pragma unroll
      for (int nt = 0; nt < 4; ++nt) {
        u16x4 pk4;
        #pragma unroll
        for (int i = 0; i < 4; ++i) {
          float pe = exp2f(s[nt][i] - m_i[qs]);   // masked: huge negative -> exact 0
          psum += pe;
          pk4[i] = f2bf(pe);
        }
        *(u16x4*)&p_s[w][r][nt * 16 + g * 4] = pk4;
      }
      psum += __shfl_xor(psum, 16);
      psum += __shfl_xor(psum, 32);
      l_i[qs] += psum;

      // ---- PV (2 x b64 p reads; per-wave roundtrip ordered by lgkmcnt) ----
      __builtin_amdgcn_s_setprio(1);
      #pragma unroll
      for (int kk = 0; kk < 2; ++kk) {
        u16x4 lo = *(const u16x4*)&p_s[w][r][kk * 32 + g * 8];
        u16x4 hi = *(const u16x4*)&p_s[w][r][kk * 32 + g * 8 + 4];
        s16x8 pa = { (short)lo[0], (short)lo[1], (short)lo[2], (short)lo[3],
                     (short)hi[0], (short)hi[1], (short)hi[2], (short)hi[3] };
        #pragma unroll
        for (int nt = 0; nt < 4; ++nt)
          o_acc[qs][nt] = __builtin_amdgcn_mfma_f32_16x16x32_bf16(pa, vf[kk][nt], o_acc[qs][nt], 0, 0, 0);
      }
      __builtin_amdgcn_s_setprio(0);
    }
  }

  #pragma unroll
  for (int qs = 0; qs < 4; ++qs) {
    float lb[4];
    #pragma unroll
    for (int i = 0; i < 4; ++i) lb[i] = __shfl(l_i[qs], g * 4 + i);   // l for q = g*4+i
    #pragma unroll
    for (int i = 0; i < 4; ++i) {
      float inv = lb[i] > 0.0f ? 1.0f / lb[i] : 0.0f;
      int lq = qs * 128 + w * 16 + g * 4 + i;
      size_t rowc = (size_t)(lq * 16 + b);
      #pragma unroll
      for (int nt = 0; nt < 4; ++nt)
        ctx[rowc * HID + h * 64 + nt * 16 + r] = f2bf(o_acc[qs][nt][i] * inv);
    }
  }
}

// ---------------- LN2 (affine), bf16 in -> f32 out ---------------------------------------
__global__ __launch_bounds__(256) void k_ln2(const ushort* t0,
                                             const float* gamma, const float* beta, float* out) {
  int row = blockIdx.x, tid = threadIdx.x;
  __shared__ float red[8];
  u16x4 xa = *(const u16x4*)(t0 + (size_t)row * HID + tid * 4);
  float x[4] = { bf2f(xa[0]), bf2f(xa[1]), bf2f(xa[2]), bf2f(xa[3]) };
  float s = x[0] + x[1] + x[2] + x[3];
  #pragma unroll
  for (int m = 1; m < 64; m <<= 1) s += __shfl_xor(s, m);
  if ((tid & 63) == 0) red[tid >> 6] = s;
  __syncthreads();
  float mean = (red[0] + red[1] + red[2] + red[3]) * (1.0f / HID);
  float d[4]; float sq = 0.0f;
  #pragma unroll
  for (int j = 0; j < 4; ++j) { d[j] = x[j] - mean; sq += d[j] * d[j]; }
  #pragma unroll
  for (int m = 1; m < 64; m <<= 1) sq += __shfl_xor(sq, m);
  __syncthreads();
  if ((tid & 63) == 0) red[4 + (tid >> 6)] = sq;
  __syncthreads();
  float var = (red[4] + red[5] + red[6] + red[7]) * (1.0f / HID);
  float rs = rsqrtf(var + LNEPS);
  f32x4 o;
  #pragma unroll
  for (int j = 0; j < 4; ++j) o[j] = d[j] * rs * gamma[tid * 4 + j] + beta[tid * 4 + j];
  *(f32x4*)(out + (size_t)row * HID + tid * 4) = o;
}

// ---------------- launch -----------------------------------------------------------------
extern "C" void kernel_launch(void* const* d_in, const int* in_sizes, int n_in,
                              void* d_out, int out_size, void* d_ws, size_t ws_size,
                              hipStream_t stream) {
  (void)in_sizes; (void)n_in; (void)out_size; (void)ws_size;
  const float* hid  = (const float*)d_in[0];
  const void*  mask = d_in[1];
  const float* rel  = (const float*)d_in[2];
  const float* wqk  = (const float*)d_in[3];
  const float* bqk  = (const float*)d_in[4];
  const float* wv   = (const float*)d_in[5];
  const float* bv   = (const float*)d_in[6];
  const float* wo   = (const float*)d_in[7];
  const float* bo   = (const float*)d_in[8];
  const float* ln_g = (const float*)d_in[9];
  const float* ln_b = (const float*)d_in[10];

  char* ws = (char*)d_ws;
  ushort* wcat     = (ushort*)(ws);                 //  6,291,456
  ushort* wo_b     = (ushort*)(ws + 6291456);       //  2,097,152
  float*  bcat     = (float*) (ws + 8388608);       //     12,288
  ushort* mask01   = (ushort*)(ws + 8400896);       //     16,384 (region 32,768)
  int*    idx_tab  = (int*)   (ws + 8433664);       //      4,096
  ushort* h_ext    = (ushort*)(ws + 8437760);       // 17,039,360  (reused as ctx)
  ushort* qkv      = (ushort*)(ws + 25477120);      // 51,118,080
  ushort* qp_b     = (ushort*)(ws + 76595200);      // 16,777,216 (bf16, scale inherited)
  ushort* pk_b     = (ushort*)(ws + 93372416);      // 16,777,216 (bf16, scale + mask)
  ushort* vt       = (ushort*)(ws + 110149632);     // 16,777,216
  char*   tmpr     = (ws + 126926848);              // 33,554,432 region
  ushort* ctx = h_ext;
  ushort* kc   = (ushort*)tmpr;                     // dead once k_attn finishes
  ushort* tmp0 = (ushort*)tmpr;                     // output-GEMM bf16 result (16,777,216)

  k_pre<<<4097 + MEXT, 256, 0, stream>>>(wqk, wv, wo, wcat, wo_b, mask, bqk, bv,
                                         mask01, idx_tab, bcat, hid, rel, h_ext);
  k_gemm256<<<33 * (NQKV / 128), 512, 0, stream>>>(h_ext, wcat, bcat, qkv, MEXT, NQKV, 1024);
  k_vtpos<<<2304, 256, 0, stream>>>(qkv, mask01, vt, kc, qp_b, pk_b);
  k_attn<<<256, 512, 0, stream>>>(qkv, qp_b, pk_b, kc, vt, idx_tab, ctx);
  k_gemm_out<<<256, 512, 0, stream>>>(ctx, wo_b, bo, tmp0);
  k_ln2<<<NROWS, 256, 0, stream>>>(tmp0, ln_g, ln_b, (float*)d_out);
}

// Round 18
// 239.491 us; speedup vs baseline: 1.2560x; 1.0004x over previous
//
#include <hip/hip_runtime.h>
#include <hip/hip_bf16.h>

#define HID 1024
#define HEADS 16
#define HEAD 64
#define RELN 63
#define SEQ 512
#define BATCH 16
#define NROWS (SEQ*BATCH)      // 8192
#define MEXT 8320              // 8192 + 63, padded to 65*128
#define NQKV 3072
#define LNEPS 1e-7f
// 1/sqrt(3*64) * log2(e): folded into Q at the QKV-GEMM epilogue (base-2 domain)
#define SCALE2 (0.07216878364870323f * 1.4426950408889634f)

typedef __attribute__((ext_vector_type(4))) float  f32x4;
typedef __attribute__((ext_vector_type(8))) short  s16x8;
typedef __attribute__((ext_vector_type(4))) ushort u16x4;

static __device__ __forceinline__ ushort f2bf(float f) {
  __hip_bfloat16 h = __float2bfloat16(f);        // native RNE cvt
  return *reinterpret_cast<ushort*>(&h);
}
static __device__ __forceinline__ float bf2f(ushort u) {
  union { unsigned u; float f; } v; v.u = ((unsigned)u) << 16;
  return v.f;
}

// ---------------- fused pre-pass: weight convert (0..4095) | prep (4096) | LN1 (4097..) --
// LN1 is wave-per-row: each of 4 waves owns one full row (16 elems/lane, shuffle-only).
__global__ __launch_bounds__(256) void k_pre(const float* wqk, const float* wv, const float* wo,
                                             ushort* wcat, ushort* wo_b,
                                             const void* mask_raw, const float* bqk, const float* bv,
                                             ushort* mask01, int* idx_tab, float* bcat,
                                             const float* hid, const float* rel, ushort* h_ext) {
  int bid = blockIdx.x, tid = threadIdx.x;
  __shared__ int s_isbool;
  if (bid < 4096) {
    int c = bid * 256 + tid;    // 1,048,576 chunks of 4 elems
    f32x4 x; ushort* dst;
    if (c < 524288)      { x = *(const f32x4*)(wqk + (size_t)c * 4);            dst = wcat + (size_t)c * 4; }
    else if (c < 786432) { x = *(const f32x4*)(wv  + (size_t)(c - 524288) * 4); dst = wcat + (size_t)c * 4; }
    else                 { x = *(const f32x4*)(wo  + (size_t)(c - 786432) * 4); dst = wo_b + (size_t)(c - 786432) * 4; }
    u16x4 o = { f2bf(x[0]), f2bf(x[1]), f2bf(x[2]), f2bf(x[3]) };
    *(u16x4*)dst = o;
    return;
  }
  if (bid == 4096) {
    // ---- prep (one block) ----
    if (tid == 0) s_isbool = 0;
    __syncthreads();
    const unsigned* mu = (const unsigned*)mask_raw;
    int bad = 0;
    for (int i = tid; i < 2048; i += 256) if (mu[i] > 1u) bad = 1;
    if (bad) s_isbool = 1;              // benign race: any writer writes 1
    __syncthreads();
    int isbool = s_isbool;
    const unsigned char* m8 = (const unsigned char*)mask_raw;
    const int* m32 = (const int*)mask_raw;
    for (int i = tid; i < BATCH*SEQ; i += 256) {
      int m = isbool ? (int)m8[i] : m32[i];
      mask01[i] = m ? 1 : 0;
    }
    for (int i = tid; i < 1023; i += 256) {
      int r = i - 511;
      int a = r < 0 ? -r : r;
      int absp = (a < 16) ? 15 : (a < 511 ? a : 511);
      int idx;
      if (absp <= 16) idx = 31 + r;
      else {
        float v = logf((float)absp / 16.0f) / logf(511.0f / 16.0f) * 15.0f;
        int lp = (int)ceilf(v) + 16;
        idx = 31 + (r > 0 ? lp : -lp);
      }
      idx_tab[i] = idx;
    }
    for (int i = tid; i < 2048; i += 256) bcat[i] = bqk[i];
    for (int i = tid; i < 1024; i += 256) bcat[2048 + i] = bv[i];
    return;
  }
  // ---- LN1 wave-per-row (no affine) -> bf16, plus rel rows + zero pad ----
  int lane = tid & 63, w = tid >> 6;
  int row = (bid - 4097) * 4 + w;
  if (row >= MEXT) return;
  if (row < NROWS) {
    const float* src = hid + (size_t)row * HID;
    f32x4 x[4];
    float s = 0.0f;
    #pragma unroll
    for (int c = 0; c < 4; ++c) {
      x[c] = *(const f32x4*)(src + c * 256 + lane * 4);
      s += x[c][0] + x[c][1] + x[c][2] + x[c][3];
    }
    #pragma unroll
    for (int m = 1; m < 64; m <<= 1) s += __shfl_xor(s, m);
    float mean = s * (1.0f / HID);
    float sq = 0.0f;
    #pragma unroll
    for (int c = 0; c < 4; ++c)
      #pragma unroll
      for (int j = 0; j < 4; ++j) { float d = x[c][j] - mean; sq += d * d; }
    #pragma unroll
    for (int m = 1; m < 64; m <<= 1) sq += __shfl_xor(sq, m);
    float rs = rsqrtf(sq * (1.0f / HID) + LNEPS);
    #pragma unroll
    for (int c = 0; c < 4; ++c) {
      u16x4 o = { f2bf((x[c][0] - mean) * rs), f2bf((x[c][1] - mean) * rs),
                  f2bf((x[c][2] - mean) * rs), f2bf((x[c][3] - mean) * rs) };
      *(u16x4*)(h_ext + (size_t)row * HID + c * 256 + lane * 4) = o;
    }
  } else if (row < NROWS + RELN) {
    const float* src = rel + (size_t)(row - NROWS) * HID;
    #pragma unroll
    for (int c = 0; c < 4; ++c) {
      f32x4 x = *(const f32x4*)(src + c * 256 + lane * 4);
      u16x4 o = { f2bf(x[0]), f2bf(x[1]), f2bf(x[2]), f2bf(x[3]) };
      *(u16x4*)(h_ext + (size_t)row * HID + c * 256 + lane * 4) = o;
    }
  } else {
    u16x4 z = { 0, 0, 0, 0 };
    #pragma unroll
    for (int c = 0; c < 4; ++c)
      *(u16x4*)(h_ext + (size_t)row * HID + c * 256 + lane * 4) = z;
  }
}

// ---------------- QKV GEMM: 256x128 tile, 8 waves, BK=64, swizzled global_load_lds -------
// Q columns (col<1024) pre-scaled by SCALE2 at the epilogue (base-2 attention domain).
__global__ __launch_bounds__(512) void k_gemm256(const ushort* A, const ushort* Bw, const float* bias,
                                                 ushort* Cb, int M, int N, int K) {
  __shared__ char smem[49152];
  char* As = smem;              // 256 x 64 bf16 = 32 KB
  char* Bs = smem + 32768;      // 128 x 64 bf16 = 16 KB
  int tid = threadIdx.x, lane = tid & 63, w = tid >> 6;
  int nbn = N >> 7;
  int per = gridDim.x >> 3;
  int gl = (blockIdx.x & 7) * per + (blockIdx.x >> 3);
  int bm = gl / nbn, bn = gl % nbn;
  int wr = w >> 1, wc = w & 1;           // 4x2 wave grid, 64x64 per wave
  int g = lane >> 4, r = lane & 15;
  f32x4 acc[4][4] = {};
  for (int ko = 0; ko < K; ko += 64) {
    __syncthreads();
    #pragma unroll
    for (int c = 0; c < 4; ++c) {        // A: 2048 chunks of 16B
      int chunk = c * 512 + tid;
      int row = chunk >> 3;
      int kbs = ((chunk & 7) << 4) ^ ((row & 7) << 4);
      int ar = bm * 256 + row; ar = ar < M ? ar : M - 1;
      const char* gA = (const char*)(A + (size_t)ar * K + ko) + kbs;
      __builtin_amdgcn_global_load_lds((const __attribute__((address_space(1))) void*)gA,
                                       (__attribute__((address_space(3))) void*)(As + c * 8192 + w * 1024),
                                       16, 0, 0);
    }
    #pragma unroll
    for (int c = 0; c < 2; ++c) {        // B: 1024 chunks of 16B
      int chunk = c * 512 + tid;
      int row = chunk >> 3;
      int kbs = ((chunk & 7) << 4) ^ ((row & 7) << 4);
      const char* gB = (const char*)(Bw + (size_t)(bn * 128 + row) * K + ko) + kbs;
      __builtin_amdgcn_global_load_lds((const __attribute__((address_space(1))) void*)gB,
                                       (__attribute__((address_space(3))) void*)(Bs + c * 8192 + w * 1024),
                                       16, 0, 0);
    }
    __syncthreads();
    #pragma unroll
    for (int kk = 0; kk < 2; ++kk) {
      s16x8 af[4], bf[4];
      #pragma unroll
      for (int mt = 0; mt < 4; ++mt) {
        int row = wr * 64 + mt * 16 + r;
        int kb = (kk * 64 + g * 16) ^ ((row & 7) << 4);
        af[mt] = *(const s16x8*)(As + row * 128 + kb);
      }
      #pragma unroll
      for (int nt = 0; nt < 4; ++nt) {
        int row = wc * 64 + nt * 16 + r;
        int kb = (kk * 64 + g * 16) ^ ((row & 7) << 4);
        bf[nt] = *(const s16x8*)(Bs + row * 128 + kb);
      }
      #pragma unroll
      for (int mt = 0; mt < 4; ++mt)
        #pragma unroll
        for (int nt = 0; nt < 4; ++nt)
          acc[mt][nt] = __builtin_amdgcn_mfma_f32_16x16x32_bf16(af[mt], bf[nt], acc[mt][nt], 0, 0, 0);
    }
  }
  #pragma unroll
  for (int nt = 0; nt < 4; ++nt) {
    int col = bn * 128 + wc * 64 + nt * 16 + r;
    float bvv = bias[col];
    float sc = (col < 1024) ? SCALE2 : 1.0f;   // fold attention scale into Q (and qpos)
    #pragma unroll
    for (int mt = 0; mt < 4; ++mt) {
      int row0 = bm * 256 + wr * 64 + mt * 16 + g * 4;
      #pragma unroll
      for (int i = 0; i < 4; ++i) {
        int row = row0 + i;
        if (row < M) Cb[(size_t)row * N + col] = f2bf((acc[mt][nt][i] + bvv) * sc);
      }
    }
  }
}

// ---------------- output GEMM: 256x128 tile, NO split-K, grid 256 = 1 block/CU -----------
__global__ __launch_bounds__(512) void k_gemm_out(const ushort* A, const ushort* Bw, const float* bias,
                                                  ushort* C) {
  const int N = 1024, K = 1024;
  __shared__ char smem[49152];
  char* As = smem;              // 256 x 64 bf16 = 32 KB
  char* Bs = smem + 32768;      // 128 x 64 bf16 = 16 KB
  int tid = threadIdx.x, lane = tid & 63, w = tid >> 6;
  int per = gridDim.x >> 3;
  int gl = (blockIdx.x & 7) * per + (blockIdx.x >> 3);
  int bm = gl >> 3, bn = gl & 7;         // bm-major per XCD chunk (A panel shared)
  int wr = w >> 1, wc = w & 1;
  int g = lane >> 4, r = lane & 15;
  f32x4 acc[4][4] = {};
  for (int ko = 0; ko < K; ko += 64) {
    __syncthreads();
    #pragma unroll
    for (int c = 0; c < 4; ++c) {        // A: 2048 chunks of 16B
      int chunk = c * 512 + tid;
      int row = chunk >> 3;
      int kbs = ((chunk & 7) << 4) ^ ((row & 7) << 4);
      const char* gA = (const char*)(A + (size_t)(bm * 256 + row) * K + ko) + kbs;
      __builtin_amdgcn_global_load_lds((const __attribute__((address_space(1))) void*)gA,
                                       (__attribute__((address_space(3))) void*)(As + c * 8192 + w * 1024),
                                       16, 0, 0);
    }
    #pragma unroll
    for (int c = 0; c < 2; ++c) {        // B: 1024 chunks of 16B
      int chunk = c * 512 + tid;
      int row = chunk >> 3;
      int kbs = ((chunk & 7) << 4) ^ ((row & 7) << 4);
      const char* gB = (const char*)(Bw + (size_t)(bn * 128 + row) * K + ko) + kbs;
      __builtin_amdgcn_global_load_lds((const __attribute__((address_space(1))) void*)gB,
                                       (__attribute__((address_space(3))) void*)(Bs + c * 8192 + w * 1024),
                                       16, 0, 0);
    }
    __syncthreads();
    #pragma unroll
    for (int kk = 0; kk < 2; ++kk) {
      s16x8 af[4], bf[4];
      #pragma unroll
      for (int mt = 0; mt < 4; ++mt) {
        int row = wr * 64 + mt * 16 + r;
        int kb = (kk * 64 + g * 16) ^ ((row & 7) << 4);
        af[mt] = *(const s16x8*)(As + row * 128 + kb);
      }
      #pragma unroll
      for (int nt = 0; nt < 4; ++nt) {
        int row = wc * 64 + nt * 16 + r;
        int kb = (kk * 64 + g * 16) ^ ((row & 7) << 4);
        bf[nt] = *(const s16x8*)(Bs + row * 128 + kb);
      }
      #pragma unroll
      for (int mt = 0; mt < 4; ++mt)
        #pragma unroll
        for (int nt = 0; nt < 4; ++nt)
          acc[mt][nt] = __builtin_amdgcn_mfma_f32_16x16x32_bf16(af[mt], bf[nt], acc[mt][nt], 0, 0, 0);
    }
  }
  #pragma unroll
  for (int nt = 0; nt < 4; ++nt) {
    int col = bn * 128 + wc * 64 + nt * 16 + r;
    float bvv = bias[col];
    #pragma unroll
    for (int mt = 0; mt < 4; ++mt) {
      int row0 = bm * 256 + wr * 64 + mt * 16 + g * 4;
      #pragma unroll
      for (int i = 0; i < 4; ++i)
        C[(size_t)(row0 + i) * N + col] = f2bf(acc[mt][nt][i] + bvv);
    }
  }
}

// ---------------- fused: V transpose + K repack (blocks <2048) | pos tables (>=2048) -----
__global__ __launch_bounds__(256) void k_vtpos(const ushort* qkv, const ushort* mask01,
                                               ushort* vt, ushort* kc, ushort* qp, ushort* pk) {
  int bid = blockIdx.x, tid = threadIdx.x;
  if (bid < 2048) {
    // ---- V transpose + K repack: vt[b,h,d,l], kc[b,h,l,d] ----
    int bh = bid >> 3, lt = bid & 7;
    int b = bh >> 4, h = bh & 15;
    __shared__ ushort tile[64][72];
    #pragma unroll
    for (int c = 0; c < 2; ++c) {
      int e = (c * 256 + tid) * 8;
      int l = e >> 6, d0 = e & 63;
      size_t row = (size_t)((lt * 64 + l) * 16 + b);
      s16x8 kv = *(const s16x8*)(qkv + row * NQKV + 1024 + h * 64 + d0);
      *(s16x8*)(kc + ((size_t)bh * SEQ + lt * 64 + l) * 64 + d0) = kv;   // contiguous K rows
      *(s16x8*)&tile[l][d0] = *(const s16x8*)(qkv + row * NQKV + 2048 + h * 64 + d0);
    }
    __syncthreads();
    #pragma unroll
    for (int c = 0; c < 2; ++c) {
      int e = (c * 256 + tid) * 8;
      int d = e >> 6, l0 = e & 63;
      ushort tmp[8];
      #pragma unroll
      for (int j = 0; j < 8; ++j) tmp[j] = tile[l0 + j][d];
      *(s16x8*)(vt + (size_t)(bh * 64 + d) * SEQ + lt * 64 + l0) = *(s16x8*)tmp;
    }
    return;
  }
  // ---- positional score tables (bf16, scale inherited from Q, mask baked into pk) ----
  int bh = bid - 2048;
  int b = bh >> 4, h = bh & 15;
  int lane = tid & 63, w = tid >> 6;
  int g = lane >> 4, r = lane & 15;
  __shared__ ushort mb[512];
  for (int i = tid; i < 512; i += 256) mb[i] = mask01[b * SEQ + i];
  __syncthreads();
  s16x8 bkp[4][2], bqp[4][2];   // kpos / qpos B-fragments (t = nt*16+r)
  #pragma unroll
  for (int nt = 0; nt < 4; ++nt)
    #pragma unroll
    for (int kk = 0; kk < 2; ++kk) {
      size_t rowp = (size_t)(NROWS + nt * 16 + r);
      int colq = h * 64 + kk * 32 + g * 8;
      bqp[nt][kk] = *(const s16x8*)(qkv + rowp * NQKV + colq);          // qpos (pre-scaled)
      bkp[nt][kk] = *(const s16x8*)(qkv + rowp * NQKV + 1024 + colq);   // kpos (unscaled)
    }
  for (int cc = 0; cc < 8; ++cc) {
    int rowbase = cc * 64 + w * 16;
    s16x8 aq[2], ak[2];
    #pragma unroll
    for (int kk = 0; kk < 2; ++kk) {
      size_t rowq = (size_t)((rowbase + r) * 16 + b);
      int colq = h * 64 + kk * 32 + g * 8;
      aq[kk] = *(const s16x8*)(qkv + rowq * NQKV + colq);               // q (pre-scaled)
      ak[kk] = *(const s16x8*)(qkv + rowq * NQKV + 1024 + colq);        // k (unscaled)
    }
    f32x4 accq[4] = {}, acck[4] = {};
    #pragma unroll
    for (int kk = 0; kk < 2; ++kk)
      #pragma unroll
      for (int nt = 0; nt < 4; ++nt) {
        accq[nt] = __builtin_amdgcn_mfma_f32_16x16x32_bf16(aq[kk], bkp[nt][kk], accq[nt], 0, 0, 0);
        acck[nt] = __builtin_amdgcn_mfma_f32_16x16x32_bf16(ak[kk], bqp[nt][kk], acck[nt], 0, 0, 0);
      }
    #pragma unroll
    for (int nt = 0; nt < 4; ++nt)
      #pragma unroll
      for (int i = 0; i < 4; ++i) {
        int q = rowbase + g * 4 + i;
        int t = nt * 16 + r;
        float biasv = mb[q] ? -1e9f : 0.0f;          // key-mask baked into pk rows
        qp[(size_t)bh * SEQ * 64 + q * 64 + t] = f2bf(accq[nt][i]);
        pk[(size_t)bh * SEQ * 64 + q * 64 + t] = f2bf(acck[nt][i] + biasv);
      }
  }
}

// ---------------- fused attention: whole-bh blocks (grid 256), barrier-free --------------
__global__ __launch_bounds__(512) void k_attn(const ushort* qkv, const ushort* qp_all, const ushort* pk_all,
                                              const ushort* kc, const ushort* vt,
                                              const int* idx_tab, ushort* ctx) {
  int bid = blockIdx.x;
  int bh = (bid & 7) * 32 + (bid >> 3);    // XCD-chunked over the 256 (b,h) pairs
  int b = bh >> 4, h = bh & 15;
  int tid = threadIdx.x, lane = tid & 63, w = tid >> 6;
  int g = lane >> 4, r = lane & 15;

  __shared__ ushort pk_f[512][68];   // 69,632 B  full-k pk table
  __shared__ ushort qp_f[512][68];   // 69,632 B  full-q qp table
  __shared__ ushort p_s[8][16][68];  // 17,408 B  per-wave P staging (stride 68: conflict-free)
  __shared__ ushort idx_s[1024];     //  2,048 B  -> total 158,720 B (<= 160 KiB)

  const ushort* qpsrc = qp_all + (size_t)bh * SEQ * 64;
  const ushort* pksrc = pk_all + (size_t)bh * SEQ * 64;
  const char*   kcb   = (const char*)(kc + (size_t)bh * SEQ * 64);   // [l][d] 128B rows

  // ---- prologue: stage qp(512), pk(512), idx; load aq; ONE barrier ----
  #pragma unroll
  for (int c = 0; c < 8; ++c) {            // 4096 chunks of 8 u16 each table
    int chunk = c * 512 + tid;
    int row = chunk >> 3, col8 = (chunk & 7) * 8;
    s16x8 vq = *(const s16x8*)(qpsrc + (size_t)row * 64 + col8);
    s16x8 vp = *(const s16x8*)(pksrc + (size_t)row * 64 + col8);
    u16x4 qlo = { (ushort)vq[0], (ushort)vq[1], (ushort)vq[2], (ushort)vq[3] };
    u16x4 qhi = { (ushort)vq[4], (ushort)vq[5], (ushort)vq[6], (ushort)vq[7] };
    u16x4 plo = { (ushort)vp[0], (ushort)vp[1], (ushort)vp[2], (ushort)vp[3] };
    u16x4 phi = { (ushort)vp[4], (ushort)vp[5], (ushort)vp[6], (ushort)vp[7] };
    *(u16x4*)&qp_f[row][col8] = qlo;
    *(u16x4*)&qp_f[row][col8 + 4] = qhi;
    *(u16x4*)&pk_f[row][col8] = plo;
    *(u16x4*)&pk_f[row][col8 + 4] = phi;
  }
  for (int i = tid; i < 1023; i += 512) idx_s[i] = (ushort)idx_tab[i];
  s16x8 aq[4][2];                          // [qs][kk] Q fragments (pre-scaled by SCALE2)
  #pragma unroll
  for (int qs = 0; qs < 4; ++qs)
    #pragma unroll
    for (int kk = 0; kk < 2; ++kk) {
      int qglob = qs * 128 + w * 16 + r;
      aq[qs][kk] = *(const s16x8*)(qkv + ((size_t)qglob * 16 + b) * NQKV + h * 64 + kk * 32 + g * 8);
    }
  __syncthreads();   // the ONLY barrier

  float m_i[4] = { -3e38f, -3e38f, -3e38f, -3e38f }, l_i[4] = { 0.0f, 0.0f, 0.0f, 0.0f };
  f32x4 o_acc[4][4] = {};

  for (int kt = 0; kt < 8; ++kt) {
    // K and V fragments straight from global (L2-shared across the block's 8 waves)
    s16x8 kf[4][2], vf[2][4];
    #pragma unroll
    for (int nt = 0; nt < 4; ++nt)
      #pragma unroll
      for (int kk = 0; kk < 2; ++kk)
        kf[nt][kk] = *(const s16x8*)(kcb + (size_t)(kt * 64 + nt * 16 + r) * 128 + kk * 64 + g * 16);
    #pragma unroll
    for (int kk = 0; kk < 2; ++kk)
      #pragma unroll
      for (int nt = 0; nt < 4; ++nt)
        vf[kk][nt] = *(const s16x8*)(vt + (size_t)(bh * 64 + nt * 16 + r) * SEQ + kt * 64 + kk * 32 + g * 8);

    #pragma unroll
    for (int qs = 0; qs < 4; ++qs) {
      // ---- swapped QK^T: lane holds S^T for q = r, k = nt*16+g*4+i ----
      f32x4 s[4];
      __builtin_amdgcn_s_setprio(1);
      #pragma unroll
      for (int nt = 0; nt < 4; ++nt) {
        f32x4 a = {};
        #pragma unroll
        for (int kk = 0; kk < 2; ++kk)
          a = __builtin_amdgcn_mfma_f32_16x16x32_bf16(kf[nt][kk], aq[qs][kk], a, 0, 0, 0);   // A=K, B=Q
        s[nt] = a;
      }
      __builtin_amdgcn_s_setprio(0);

      // ---- gather: v = c2c + qp_f[q][t] + pk_f[k][t]  (scale pre-folded, mask in pk) ----
      const ushort* qprow = &qp_f[qs * 128 + w * 16 + r][0];
      const int qg511 = qs * 128 + w * 16 + r + 511;
      float mloc0 = -3e38f, mloc1 = -3e38f;
      #pragma unroll
      for (int nt = 0; nt < 4; ++nt) {
        #pragma unroll
        for (int i = 0; i < 4; ++i) {
          int kg = kt * 64 + nt * 16 + g * 4 + i;
          int t = idx_s[qg511 - kg];
          float v = s[nt][i] + bf2f(qprow[t]) + bf2f(pk_f[kg][t]);
          s[nt][i] = v;
        }
        // fmaxf triples -> v_max3_f32 (T17)
        mloc0 = fmaxf(mloc0, fmaxf(fmaxf(s[nt][0], s[nt][1]), s[nt][2]));
        mloc1 = fmaxf(mloc1, s[nt][3]);
      }
      float m_loc = fmaxf(mloc0, mloc1);

      // ---- row max across the 4 g-lanes holding q = r ----
      float mx = fmaxf(m_loc, __shfl_xor(m_loc, 16));
      mx = fmaxf(mx, __shfl_xor(mx, 32));

      // ---- T13 defer-rescale (base-2 threshold 8) ----
      if (__any(mx > m_i[qs] + 8.0f)) {
        float mnew = fmaxf(m_i[qs], mx);
        float rs = exp2f(m_i[qs] - mnew);
        m_i[qs] = mnew;
        l_i[qs] *= rs;
        float rsb[4];
        #pragma unroll
        for (int i = 0; i < 4; ++i) rsb[i] = __shfl(rs, g * 4 + i);   // rs for q = g*4+i
        #pragma unroll
        for (int nt = 0; nt < 4; ++nt)
          #pragma unroll
          for (int i = 0; i < 4; ++i) o_acc[qs][nt][i] *= rsb[i];
      }

      // ---- exp2 + P pack (b64 LDS writes), psum ----
      float psum = 0.0f;
      #pragma unroll
      for (int nt = 0; nt < 4; ++nt) {
        u16x4 pk4;
        #pragma unroll
        for (int i = 0; i < 4; ++i) {
          float pe = exp2f(s[nt][i] - m_i[qs]);   // masked: huge negative -> exact 0
          psum += pe;
          pk4[i] = f2bf(pe);
        }
        *(u16x4*)&p_s[w][r][nt * 16 + g * 4] = pk4;
      }
      psum += __shfl_xor(psum, 16);
      psum += __shfl_xor(psum, 32);
      l_i[qs] += psum;

      // ---- PV (2 x b64 p reads; per-wave roundtrip ordered by lgkmcnt) ----
      __builtin_amdgcn_s_setprio(1);
      #pragma unroll
      for (int kk = 0; kk < 2; ++kk) {
        u16x4 lo = *(const u16x4*)&p_s[w][r][kk * 32 + g * 8];
        u16x4 hi = *(const u16x4*)&p_s[w][r][kk * 32 + g * 8 + 4];
        s16x8 pa = { (short)lo[0], (short)lo[1], (short)lo[2], (short)lo[3],
                     (short)hi[0], (short)hi[1], (short)hi[2], (short)hi[3] };
        #pragma unroll
        for (int nt = 0; nt < 4; ++nt)
          o_acc[qs][nt] = __builtin_amdgcn_mfma_f32_16x16x32_bf16(pa, vf[kk][nt], o_acc[qs][nt], 0, 0, 0);
      }
      __builtin_amdgcn_s_setprio(0);
    }
  }

  #pragma unroll
  for (int qs = 0; qs < 4; ++qs) {
    float lb[4];
    #pragma unroll
    for (int i = 0; i < 4; ++i) lb[i] = __shfl(l_i[qs], g * 4 + i);   // l for q = g*4+i
    #pragma unroll
    for (int i = 0; i < 4; ++i) {
      float inv = lb[i] > 0.0f ? 1.0f / lb[i] : 0.0f;
      int lq = qs * 128 + w * 16 + g * 4 + i;
      size_t rowc = (size_t)(lq * 16 + b);
      #pragma unroll
      for (int nt = 0; nt < 4; ++nt)
        ctx[rowc * HID + h * 64 + nt * 16 + r] = f2bf(o_acc[qs][nt][i] * inv);
    }
  }
}

// ---------------- LN2 (affine), wave-per-row, bf16 in -> f32 out -------------------------
// 4 waves/block, one full row per wave: shuffle-only reductions, no LDS, no barriers.
__global__ __launch_bounds__(256) void k_ln2(const ushort* t0,
                                             const float* gamma, const float* beta, float* out) {
  int lane = threadIdx.x & 63, w = threadIdx.x >> 6;
  int row = blockIdx.x * 4 + w;
  const ushort* src = t0 + (size_t)row * HID;
  float x[4][4];
  float s = 0.0f;
  #pragma unroll
  for (int c = 0; c < 4; ++c) {
    u16x4 xb = *(const u16x4*)(src + c * 256 + lane * 4);
    #pragma unroll
    for (int j = 0; j < 4; ++j) { x[c][j] = bf2f(xb[j]); s += x[c][j]; }
  }
  #pragma unroll
  for (int m = 1; m < 64; m <<= 1) s += __shfl_xor(s, m);
  float mean = s * (1.0f / HID);
  float sq = 0.0f;
  #pragma unroll
  for (int c = 0; c < 4; ++c)
    #pragma unroll
    for (int j = 0; j < 4; ++j) { float d = x[c][j] - mean; sq += d * d; }
  #pragma unroll
  for (int m = 1; m < 64; m <<= 1) sq += __shfl_xor(sq, m);
  float rs = rsqrtf(sq * (1.0f / HID) + LNEPS);
  #pragma unroll
  for (int c = 0; c < 4; ++c) {
    int col = c * 256 + lane * 4;
    f32x4 gm = *(const f32x4*)(gamma + col);
    f32x4 bt = *(const f32x4*)(beta + col);
    f32x4 o;
    #pragma unroll
    for (int j = 0; j < 4; ++j) o[j] = (x[c][j] - mean) * rs * gm[j] + bt[j];
    *(f32x4*)(out + (size_t)row * HID + col) = o;
  }
}

// ---------------- launch -----------------------------------------------------------------
extern "C" void kernel_launch(void* const* d_in, const int* in_sizes, int n_in,
                              void* d_out, int out_size, void* d_ws, size_t ws_size,
                              hipStream_t stream) {
  (void)in_sizes; (void)n_in; (void)out_size; (void)ws_size;
  const float* hid  = (const float*)d_in[0];
  const void*  mask = d_in[1];
  const float* rel  = (const float*)d_in[2];
  const float* wqk  = (const float*)d_in[3];
  const float* bqk  = (const float*)d_in[4];
  const float* wv   = (const float*)d_in[5];
  const float* bv   = (const float*)d_in[6];
  const float* wo   = (const float*)d_in[7];
  const float* bo   = (const float*)d_in[8];
  const float* ln_g = (const float*)d_in[9];
  const float* ln_b = (const float*)d_in[10];

  char* ws = (char*)d_ws;
  ushort* wcat     = (ushort*)(ws);                 //  6,291,456
  ushort* wo_b     = (ushort*)(ws + 6291456);       //  2,097,152
  float*  bcat     = (float*) (ws + 8388608);       //     12,288
  ushort* mask01   = (ushort*)(ws + 8400896);       //     16,384 (region 32,768)
  int*    idx_tab  = (int*)   (ws + 8433664);       //      4,096
  ushort* h_ext    = (ushort*)(ws + 8437760);       // 17,039,360  (reused as ctx)
  ushort* qkv      = (ushort*)(ws + 25477120);      // 51,118,080
  ushort* qp_b     = (ushort*)(ws + 76595200);      // 16,777,216 (bf16, scale inherited)
  ushort* pk_b     = (ushort*)(ws + 93372416);      // 16,777,216 (bf16, scale + mask)
  ushort* vt       = (ushort*)(ws + 110149632);     // 16,777,216
  char*   tmpr     = (ws + 126926848);              // 33,554,432 region
  ushort* ctx = h_ext;
  ushort* kc   = (ushort*)tmpr;                     // dead once k_attn finishes
  ushort* tmp0 = (ushort*)tmpr;                     // output-GEMM bf16 result (16,777,216)

  k_pre<<<4097 + MEXT / 4, 256, 0, stream>>>(wqk, wv, wo, wcat, wo_b, mask, bqk, bv,
                                             mask01, idx_tab, bcat, hid, rel, h_ext);
  k_gemm256<<<33 * (NQKV / 128), 512, 0, stream>>>(h_ext, wcat, bcat, qkv, MEXT, NQKV, 1024);
  k_vtpos<<<2304, 256, 0, stream>>>(qkv, mask01, vt, kc, qp_b, pk_b);
  k_attn<<<256, 512, 0, stream>>>(qkv, qp_b, pk_b, kc, vt, idx_tab, ctx);
  k_gemm_out<<<256, 512, 0, stream>>>(ctx, wo_b, bo, tmp0);
  k_ln2<<<NROWS / 4, 256, 0, stream>>>(tmp0, ln_g, ln_b, (float*)d_out);
}